// Round 9
// baseline (591.303 us; speedup 1.0000x reference)
//
#include <hip/hip_runtime.h>

typedef unsigned int u32;
typedef unsigned long long u64;
typedef _Float16 f16;
typedef __attribute__((ext_vector_type(2))) _Float16 f16x2;
typedef __attribute__((ext_vector_type(4))) _Float16 f16x4;
typedef __attribute__((ext_vector_type(8))) _Float16 f16x8;
typedef __attribute__((ext_vector_type(4))) float f32x4;
typedef __attribute__((ext_vector_type(2))) double f64x2;

// Problem constants: B=2, T=2048, D=2048, LAT=512, H=16, HD=128, NKV=4, G=4,
// SEL_DIM=64, TOPK=64, NROW = 4096

// su storage swizzle: spreads the tid*8+e LDS sweep across 16 banks.
__device__ __forceinline__ int suX(int jj) { return jj ^ ((jj >> 4) & 7); }

// ------------------------------------------------- transpose + cast f32->f16
__global__ __launch_bounds__(256) void k_transpose_cast(const float* __restrict__ in,
                                                        f16* __restrict__ out, int R, int C)
{
  __shared__ float tile[32][33];
  int c0 = blockIdx.x * 32, r0 = blockIdx.y * 32;
  int tx = threadIdx.x & 31, ty = threadIdx.x >> 5;  // ty 0..7
  #pragma unroll
  for (int i = ty; i < 32; i += 8) tile[i][tx] = in[(size_t)(r0 + i) * C + c0 + tx];
  __syncthreads();
  #pragma unroll
  for (int i = ty; i < 32; i += 8) out[(size_t)(c0 + i) * R + r0 + tx] = (f16)tile[tx][i];
}

// ------------------------------------------------------------- cast f32->f16
__global__ __launch_bounds__(256) void k_cast_f16(const float* __restrict__ in,
                                                  f16* __restrict__ out, int n4)
{
  int i = blockIdx.x * 256 + threadIdx.x;
  if (i >= n4) return;
  f32x4 v = *(const f32x4*)&in[(size_t)i * 4];
  f16x4 h; h.x = (f16)v.x; h.y = (f16)v.y; h.z = (f16)v.z; h.w = (f16)v.w;
  *(f16x4*)&out[(size_t)i * 4] = h;
}

// ------------------------------------------------------------- fp64 selector weights
__global__ void k_prep_sel(const float* __restrict__ Wq, const float* __restrict__ Wkd,
                           const float* __restrict__ Wku, double* __restrict__ Bsel)
{
  const int k = blockIdx.x;   // 0..2047
  const int j = threadIdx.x;  // 0..63
  Bsel[(size_t)k * 128 + j] = (double)Wq[(size_t)k * 2048 + j];
  double s = 0.0;
  for (int l = 0; l < 512; ++l)
    s = fma((double)Wkd[(size_t)k * 512 + l], (double)Wku[(size_t)l * 1024 + j], s);
  Bsel[(size_t)k * 128 + 64 + j] = s;
}

__global__ void k_bias_sel(const float* __restrict__ bq, const float* __restrict__ bkd,
                           const float* __restrict__ Wku, const float* __restrict__ bku,
                           double* __restrict__ bsel)
{
  int j = threadIdx.x;  // 0..127
  if (j < 64) {
    bsel[j] = (double)bq[j];
  } else {
    int jj = j - 64;
    double s = (double)bku[jj];
    for (int l = 0; l < 512; ++l)
      s = fma((double)bkd[l], (double)Wku[(size_t)l * 1024 + jj], s);
    bsel[j] = s;
  }
}

// ------------------------------------------------------------- fp64 selector GEMM, split-K
__global__ __launch_bounds__(256) void k_gemm_sel_f64(const float* __restrict__ A,
                                                      const double* __restrict__ Bsel,
                                                      double* __restrict__ partial)
{
  __shared__ double As[32][33];
  __shared__ double Bs[32][66];
  const int m0 = blockIdx.x * 32, n0 = blockIdx.y * 64;
  const int kbase = blockIdx.z * 512, kend = kbase + 512;
  const int tid = threadIdx.x;
  const int tx = tid & 15, ty = tid >> 4;
  const int ar = tid >> 3, ac4 = (tid & 7) * 4;
  double acc[2][4] = {};

  f32x4 aN = *(const f32x4*)&A[(size_t)(m0 + ar) * 2048 + kbase + ac4];
  f64x2 bN[4];
  #pragma unroll
  for (int it = 0; it < 4; ++it) {
    int c = it * 256 + tid; int kk = c >> 5, n2 = (c & 31) * 2;
    bN[it] = *(const f64x2*)&Bsel[(size_t)(kbase + kk) * 128 + n0 + n2];
  }
  for (int k0 = kbase; k0 < kend; k0 += 32) {
    __syncthreads();
    As[ar][ac4] = (double)aN.x; As[ar][ac4 + 1] = (double)aN.y;
    As[ar][ac4 + 2] = (double)aN.z; As[ar][ac4 + 3] = (double)aN.w;
    #pragma unroll
    for (int it = 0; it < 4; ++it) {
      int c = it * 256 + tid; int kk = c >> 5, n2 = (c & 31) * 2;
      Bs[kk][n2] = bN[it].x; Bs[kk][n2 + 1] = bN[it].y;
    }
    __syncthreads();
    if (k0 + 32 < kend) {
      aN = *(const f32x4*)&A[(size_t)(m0 + ar) * 2048 + k0 + 32 + ac4];
      #pragma unroll
      for (int it = 0; it < 4; ++it) {
        int c = it * 256 + tid; int kk = c >> 5, n2 = (c & 31) * 2;
        bN[it] = *(const f64x2*)&Bsel[(size_t)(k0 + 32 + kk) * 128 + n0 + n2];
      }
    }
    #pragma unroll
    for (int kk = 0; kk < 32; ++kk) {
      double a0 = As[ty * 2][kk], a1 = As[ty * 2 + 1][kk];
      f64x2 b01 = *(const f64x2*)&Bs[kk][tx * 4];
      f64x2 b23 = *(const f64x2*)&Bs[kk][tx * 4 + 2];
      acc[0][0] = fma(a0, b01.x, acc[0][0]); acc[0][1] = fma(a0, b01.y, acc[0][1]);
      acc[0][2] = fma(a0, b23.x, acc[0][2]); acc[0][3] = fma(a0, b23.y, acc[0][3]);
      acc[1][0] = fma(a1, b01.x, acc[1][0]); acc[1][1] = fma(a1, b01.y, acc[1][1]);
      acc[1][2] = fma(a1, b23.x, acc[1][2]); acc[1][3] = fma(a1, b23.y, acc[1][3]);
    }
  }
  double* op = partial + (size_t)blockIdx.z * 4096 * 128;
  #pragma unroll
  for (int i = 0; i < 2; ++i) {
    int row = m0 + ty * 2 + i;
    #pragma unroll
    for (int j = 0; j < 4; ++j) {
      int n = n0 + tx * 4 + j;
      op[(size_t)row * 128 + n] = acc[i][j];
    }
  }
}

// Stage 2: fixed-order reduction of the 4 K-slice partials + bias.
__global__ __launch_bounds__(256) void k_sel_reduce(const double* __restrict__ partial,
                                                    const double* __restrict__ bias,
                                                    double* __restrict__ qs64,
                                                    double* __restrict__ ks64)
{
  const int idx = blockIdx.x * 256 + threadIdx.x;  // 0 .. 4096*128-1
  const int row = idx >> 7, n = idx & 127;
  const size_t S = 4096 * 128;
  double v = ((partial[idx] + partial[S + idx]) + partial[2 * S + idx]) + partial[3 * S + idx];
  v += bias[n];
  if (n < 64) qs64[(size_t)row * 64 + n] = v;
  else        ks64[(size_t)row * 64 + (n - 64)] = v;
}

// ------------------------------------------------------------- fp64 transpose
__global__ __launch_bounds__(256) void k_transpose64(const double* __restrict__ in,
                                                     double* __restrict__ out)
{
  __shared__ double tile[32][33];
  const int bt = blockIdx.z;
  const int c0 = blockIdx.x * 32;
  const int r0 = blockIdx.y * 32;
  int tx = threadIdx.x & 31, ty = threadIdx.x >> 5;
  const double* ip = in + (size_t)bt * 2048 * 64;
  double* op = out + (size_t)bt * 64 * 2048;
  #pragma unroll
  for (int i = ty; i < 32; i += 8) tile[i][tx] = ip[(size_t)(r0 + i) * 64 + c0 + tx];
  __syncthreads();
  #pragma unroll
  for (int i = ty; i < 32; i += 8) op[(size_t)(c0 + i) * 2048 + r0 + tx] = tile[tx][i];
}

// ------------------------------------------------------------- fp16 MFMA GEMM (m97 structure)
template <bool OUTF16>
__global__ __launch_bounds__(256) void k_gemm_bt(const f16* __restrict__ A,
                                                 const f16* __restrict__ BT,
                                                 const float* __restrict__ bias,
                                                 float* __restrict__ C, f16* __restrict__ Ch,
                                                 int M, int N, int K, int lda, int ldb, int ldc)
{
  __shared__ __align__(16) f16 As[128 * 64];
  __shared__ __align__(16) f16 Bs[128 * 64];
  const int tid = threadIdx.x;
  const int lane = tid & 63;
  const int wave = tid >> 6;
  const int m0 = blockIdx.x * 128, n0 = blockIdx.y * 128;
  const int wr = (wave >> 1) * 64, wc = (wave & 1) * 64;
  const int lrow = lane & 15;
  const int kgrp = (lane >> 4) * 8;
  f32x4 acc[4][4] = {};

  for (int k0 = 0; k0 < K; k0 += 64) {
    __syncthreads();
    #pragma unroll
    for (int it = 0; it < 4; ++it) {
      int c = it * 256 + tid;
      int r = c >> 3, c8 = (c & 7) * 8;
      int lbase = (it * 256 + (tid & 192)) * 8;  // wave-uniform LDS offset
      const f16* ga = A + (size_t)(m0 + r) * lda + k0 + c8;
      __builtin_amdgcn_global_load_lds((const __attribute__((address_space(1))) u32*)ga,
                                       (__attribute__((address_space(3))) u32*)&As[lbase],
                                       16, 0, 0);
      const f16* gb = BT + (size_t)(n0 + r) * ldb + k0 + c8;
      __builtin_amdgcn_global_load_lds((const __attribute__((address_space(1))) u32*)gb,
                                       (__attribute__((address_space(3))) u32*)&Bs[lbase],
                                       16, 0, 0);
    }
    __syncthreads();
    #pragma unroll
    for (int ks = 0; ks < 2; ++ks) {
      f16x8 af[4], bfr[4];
      #pragma unroll
      for (int m = 0; m < 4; ++m)
        af[m] = *(const f16x8*)&As[(wr + m * 16 + lrow) * 64 + ks * 32 + kgrp];
      #pragma unroll
      for (int n = 0; n < 4; ++n)
        bfr[n] = *(const f16x8*)&Bs[(wc + n * 16 + lrow) * 64 + ks * 32 + kgrp];
      #pragma unroll
      for (int m = 0; m < 4; ++m)
        #pragma unroll
        for (int n = 0; n < 4; ++n)
          acc[m][n] = __builtin_amdgcn_mfma_f32_16x16x32_f16(af[m], bfr[n], acc[m][n], 0, 0, 0);
    }
  }
  const int rbase = m0 + wr + (lane >> 4) * 4;  // C/D: col=lane&15, row=(lane>>4)*4+reg [m89]
  #pragma unroll
  for (int n = 0; n < 4; ++n) {
    int col = n0 + wc + n * 16 + lrow;
    float bv = bias ? bias[col] : 0.0f;
    #pragma unroll
    for (int m = 0; m < 4; ++m) {
      #pragma unroll
      for (int j = 0; j < 4; ++j) {
        int rowi = rbase + m * 16 + j;
        float v = acc[m][n][j] + bv;
        if (OUTF16) Ch[(size_t)rowi * ldc + col] = (f16)v;
        else        C[(size_t)rowi * ldc + col] = v;
      }
    }
  }
}

// ------------------------------------------------------------- RoPE tables
__global__ void k_rope_table(float* __restrict__ rc, float* __restrict__ rs)
{
  int t = blockIdx.x, i = threadIdx.x;  // 2048 x 64
  int fi = (2 * i) & 63;
  double inv = pow(10000.0, -(double)fi / 64.0);
  double a = (double)t * inv;
  rc[t * 64 + i] = (float)cos(a);
  rs[t * 64 + i] = (float)sin(a);
}

__global__ __launch_bounds__(256) void k_rope_q(const f16* __restrict__ q,
                                                const float* __restrict__ rc,
                                                const float* __restrict__ rs,
                                                f16* __restrict__ out)
{
  int g = blockIdx.x * 256 + threadIdx.x;  // 4096*16*64
  int row = g >> 10, rem = g & 1023;
  int h = rem >> 6, i = rem & 63;
  int t = row & 2047;
  size_t base = (size_t)row * 2048 + h * 128 + 2 * i;
  f16x2 v = *(const f16x2*)&q[base];
  float x1 = (float)v.x, x2 = (float)v.y;
  float c = rc[t * 64 + i], s = rs[t * 64 + i];
  f16x2 o; o.x = (f16)(x1 * c - x2 * s); o.y = (f16)(x1 * s + x2 * c);
  *(f16x2*)&out[base] = o;
}

__global__ __launch_bounds__(256) void k_rope_kv(const f16* __restrict__ kv,
                                                 const float* __restrict__ rc,
                                                 const float* __restrict__ rs,
                                                 f16* __restrict__ kout, f16* __restrict__ vout)
{
  int g = blockIdx.x * 256 + threadIdx.x;  // 4096*4*64
  int row = g >> 8, rem = g & 255;
  int kvh = rem >> 6, i = rem & 63;
  int t = row & 2047;
  size_t kb = (size_t)row * 1024 + kvh * 128 + 2 * i;
  f16x2 kvp = *(const f16x2*)&kv[kb];
  float x1 = (float)kvp.x, x2 = (float)kvp.y;
  float c = rc[t * 64 + i], s = rs[t * 64 + i];
  size_t ob = (size_t)row * 512 + kvh * 128 + 2 * i;
  f16x2 ko; ko.x = (f16)(x1 * c - x2 * s); ko.y = (f16)(x1 * s + x2 * c);
  *(f16x2*)&kout[ob] = ko;
  f16x2 vp = *(const f16x2*)&kv[(size_t)row * 1024 + 512 + kvh * 128 + 2 * i];
  *(f16x2*)&vout[ob] = vp;
}

// ------------------------------------------------------------- exact top-64, fp64 scores
__global__ __launch_bounds__(256) void k_topk64(const double* __restrict__ qs,
                                                const double* __restrict__ ksT,
                                                int* __restrict__ selcnt,
                                                int* __restrict__ selidx)
{
  const int r0 = blockIdx.x * 2;
  const int b = r0 >> 11;
  const int t0 = r0 & 2047, t1 = t0 + 1;
  const int tid = threadIdx.x;
  if (t1 < 64) {
    for (int lr = 0; lr < 2; ++lr) {
      int t = t0 + lr;
      int* outp = selidx + (size_t)(r0 + lr) * 68;
      for (int jj = tid; jj <= t; jj += 256) outp[jj] = jj;
      if (tid == 0) selcnt[r0 + lr] = t + 1;
    }
    return;
  }
  __shared__ double qrowP[64][2];
  __shared__ u64 su[2][2048];
  __shared__ unsigned hist[256], sA[256], sB[256];
  __shared__ unsigned s_bsel, s_larger, s_cnt;
  __shared__ u64 s_thr;
  __shared__ int s_remfin;
  __shared__ int cand[128];
  __shared__ u64 ckey[128];

  if (tid < 128) qrowP[tid >> 1][tid & 1] = qs[(size_t)(r0 + (tid & 1)) * 64 + (tid >> 1)];
  __syncthreads();
  {
    const double* kb = ksT + (size_t)b * 64 * 2048;
    const int emax = t1 >> 8;
    for (int e = 0; e <= emax; ++e) {
      const int jj = e * 256 + tid;
      double acc0 = 0.0, acc1 = 0.0;
      const double* kp = kb + jj;
      #pragma unroll 16
      for (int d = 0; d < 64; ++d) {
        double kv = kp[(size_t)d * 2048];
        f64x2 qp = *(const f64x2*)&qrowP[d][0];
        acc0 = fma(qp.x, kv, acc0);
        acc1 = fma(qp.y, kv, acc1);
      }
      const int sx = suX(jj);
      u64 u0 = (u64)__double_as_longlong(acc0);
      su[0][sx] = (u0 >> 63) ? ~u0 : (u0 | 0x8000000000000000ull);
      u64 u1 = (u64)__double_as_longlong(acc1);
      su[1][sx] = (u1 >> 63) ? ~u1 : (u1 | 0x8000000000000000ull);
    }
  }
  __syncthreads();

  const int c0 = tid * 8;
  for (int lr = 0; lr < 2; ++lr) {
    const int t = t0 + lr;
    int* outp = selidx + (size_t)(r0 + lr) * 68;
    const u64* S = su[lr];
    u64 prefix = 0;
    int remaining = 64;
    int broke = 0, sh_final = 0;
    for (int byte = 7; byte >= 0; --byte) {
      const int sh = byte * 8;
      hist[tid] = 0;
      __syncthreads();
      {
        unsigned bn[8]; bool vl[8];
        #pragma unroll
        for (int e = 0; e < 8; ++e) {
          int jj = c0 + e;
          u64 u = (jj <= t) ? S[suX(jj)] : 0;
          bool ok = (jj <= t) && ((byte == 7) || (((u ^ prefix) >> (sh + 8)) == 0));
          bn[e] = (unsigned)((u >> sh) & 255);
          vl[e] = ok;
        }
        #pragma unroll
        for (int e = 0; e < 8; ++e) {
          if (vl[e]) {
            bool first = true;
            #pragma unroll
            for (int p = 0; p < 8; ++p)
              if (p < e && vl[p] && bn[p] == bn[e]) first = false;
            if (first) {
              unsigned c = 0;
              #pragma unroll
              for (int q = 0; q < 8; ++q)
                if (q >= e && vl[q] && bn[q] == bn[e]) ++c;
              atomicAdd(&hist[bn[e]], c);
            }
          }
        }
      }
      __syncthreads();
      unsigned* sp = sA; unsigned* dp = sB;
      sp[tid] = hist[tid];
      __syncthreads();
      #pragma unroll
      for (int off = 1; off < 256; off <<= 1) {
        dp[tid] = sp[tid] + ((tid + off < 256) ? sp[tid + off] : 0u);
        __syncthreads();
        unsigned* tpp = sp; sp = dp; dp = tpp;
      }
      unsigned inc = sp[tid];
      unsigned cumAbove = (tid == 255) ? 0u : sp[tid + 1];
      if ((int)cumAbove < remaining && (int)inc >= remaining) {
        s_bsel = (unsigned)tid;
        s_larger = cumAbove;
        s_cnt = inc - cumAbove;
      }
      __syncthreads();
      prefix |= ((u64)s_bsel << sh);
      remaining -= (int)s_larger;
      int cnt = (int)s_cnt;
      __syncthreads();
      if (cnt <= 128) { broke = 1; sh_final = sh; break; }
    }
    u64 thr;
    int remfin;
    if (broke) {
      unsigned cg = 0;
      #pragma unroll
      for (int e = 0; e < 8; ++e) {
        int jj = c0 + e;
        if (jj <= t && (((S[suX(jj)] ^ prefix) >> sh_final) == 0)) ++cg;
      }
      unsigned* sp = sA; unsigned* dp = sB;
      sp[tid] = cg;
      __syncthreads();
      #pragma unroll
      for (int off = 1; off < 256; off <<= 1) {
        dp[tid] = sp[tid] + ((tid >= off) ? sp[tid - off] : 0u);
        __syncthreads();
        unsigned* tpp = sp; sp = dp; dp = tpp;
      }
      const int C = (int)sp[255];
      int pos = (int)(sp[tid] - cg);
      #pragma unroll
      for (int e = 0; e < 8; ++e) {
        int jj = c0 + e;
        if (jj <= t && (((S[suX(jj)] ^ prefix) >> sh_final) == 0)) cand[pos++] = jj;
      }
      __syncthreads();
      if (tid < C) ckey[tid] = S[suX(cand[tid])];
      __syncthreads();
      if (tid < C) {
        u64 k = ckey[tid];
        int g = 0, eq = 0;
        for (int j = 0; j < C; ++j) {
          g += (ckey[j] > k) ? 1 : 0;
          eq += (ckey[j] == k) ? 1 : 0;
        }
        if (g < remaining && remaining <= g + eq) {
          s_thr = k;
          s_remfin = remaining - g;
        }
      }
      __syncthreads();
      thr = s_thr;
      remfin = s_remfin;
    } else {
      thr = prefix;
      remfin = remaining;
    }
    __syncthreads();
    unsigned cg = 0, ct_ = 0;
    #pragma unroll
    for (int e = 0; e < 8; ++e) {
      int jj = c0 + e;
      if (jj <= t) {
        u64 u = S[suX(jj)];
        cg += (u > thr) ? 1u : 0u;
        ct_ += (u == thr) ? 1u : 0u;
      }
    }
    const unsigned pack = cg | (ct_ << 16);
    {
      unsigned* sp = sA; unsigned* dp = sB;
      sp[tid] = pack;
      __syncthreads();
      #pragma unroll
      for (int off = 1; off < 256; off <<= 1) {
        dp[tid] = sp[tid] + ((tid >= off) ? sp[tid - off] : 0u);
        __syncthreads();
        unsigned* tpp = sp; sp = dp; dp = tpp;
      }
      const unsigned excl = sp[tid] - pack;
      const unsigned tot = sp[255];
      const unsigned Gtot = tot & 0xFFFFu;
      const u64 ut = S[suX(t)];
      const unsigned gt = (ut > thr) ? 1u : 0u;
      const unsigned tt = (ut == thr) ? 1u : 0u;
      const int GtotX = (int)(Gtot - gt);
      int gpos = (int)(excl & 0xFFFFu);
      int tpos = (int)(excl >> 16);
      #pragma unroll
      for (int e = 0; e < 8; ++e) {
        int jj = c0 + e;
        if (jj > t) break;
        u64 u = S[suX(jj)];
        if (u > thr) {
          if (jj != t) outp[1 + gpos] = jj;
          ++gpos;
        } else if (u == thr) {
          if (jj != t && tpos < remfin) outp[1 + GtotX + tpos] = jj;
          ++tpos;
        }
      }
      if (tid == 0) {
        outp[0] = t;
        const unsigned Ttot = tot >> 16;
        int tb = (int)(Ttot - tt);
        int emitT = tb < remfin ? tb : remfin;
        selcnt[r0 + lr] = 1 + GtotX + emitT;  // 64 or 65
      }
    }
    __syncthreads();
  }
}

// ------------------------------------------------------------- sparse attention (MFMA)
// Block per (row, kvh), 4 waves. S(16x80)=Q@K^T and O(16x128)=P@V on the matrix
// pipe (R8's version did the 4.4 GFLOP on VALU: 59% VALUBusy, MfmaUtil 0).
// A/B fragment layout = proven k_gemm_bt layout (contiguous 8 f16 at k=(l>>4)*8);
// C layout col=lane&15, row=(lane>>4)*4+reg [m89].
// Waves compute QK+softmax redundantly (no cross-wave reduce); PV split by dims.
// All padding lanes masked BEFORE use (uninit-LDS NaN safe); V padding written 0.
__global__ __launch_bounds__(256) void k_attn(const f16* __restrict__ qr,
                                              const f16* __restrict__ kr,
                                              const f16* __restrict__ vv,
                                              const int* __restrict__ selcnt,
                                              const int* __restrict__ selidx,
                                              f16* __restrict__ y)
{
  const int blk = blockIdx.x;  // row*4 + kvh
  const int row = blk >> 2, kvh = blk & 3;
  const int b = row >> 11;
  const int tid = threadIdx.x, lane = tid & 63, wave = tid >> 6;
  const int cnt = selcnt[row];
  __shared__ int sidx[68];
  __shared__ __align__(16) f16 KV[13312];      // union: Kl[80][128] | Vt[128][104]
  __shared__ __align__(16) f16 Pbuf[16 * 104]; // P in A-layout, rows 4..15 zero
  if (tid < cnt) sidx[tid] = selidx[(size_t)row * 68 + tid];
  __syncthreads();  // sidx ready

  // ---- phase 1: stage K (chunk-XOR swizzle, proven pattern); V -> regs; zero Pbuf
  for (int c = tid; c < cnt * 16; c += 256) {
    const int r = c >> 4, ch = c & 15;
    f16x8 k8 = *(const f16x8*)&kr[((size_t)(b * 2048 + sidx[r])) * 512 + kvh * 128 + ch * 8];
    *(f16x8*)&KV[r * 128 + ((ch ^ (r & 15)) * 8)] = k8;
  }
  f16x8 vreg[6];  // 96 keys x 16 chunks / 256 threads; keys >= cnt stay zero
  #pragma unroll
  for (int it = 0; it < 6; ++it) {
    const int c = it * 256 + tid;
    const int r = c >> 4, ch = c & 15;
    f16x8 z = {};
    if (r < cnt)
      z = *(const f16x8*)&vv[((size_t)(b * 2048 + sidx[r])) * 512 + kvh * 128 + ch * 8];
    vreg[it] = z;
  }
  for (int i = tid; i < 16 * 104 / 2; i += 256) ((u32*)Pbuf)[i] = 0u;
  // Q A-fragments from global (M rows 0..3 = real heads, 4..15 duplicated/finite)
  const f16* qb = qr + (size_t)row * 2048 + (4 * kvh + (lane & 3)) * 128;
  f16x8 qf[4];
  #pragma unroll
  for (int k0 = 0; k0 < 4; ++k0) qf[k0] = *(const f16x8*)&qb[k0 * 32 + (lane >> 4) * 8];
  __syncthreads();  // Kl + Pbuf-zero ready

  // ---- phase 2: QK (20 MFMA, redundant per wave), softmax, P -> Pbuf
  f32x4 sc[5];
  #pragma unroll
  for (int n = 0; n < 5; ++n) {
    f32x4 a = {0.f, 0.f, 0.f, 0.f};
    const int r = n * 16 + (lane & 15);
    #pragma unroll
    for (int k0 = 0; k0 < 4; ++k0) {
      const int ch = (k0 * 4 + (lane >> 4)) ^ (r & 15);
      f16x8 bf = *(const f16x8*)&KV[r * 128 + ch * 8];
      a = __builtin_amdgcn_mfma_f32_16x16x32_f16(qf[k0], bf, a, 0, 0, 0);
    }
    sc[n] = a;
  }
  const float SCALE = 0.08838834764831845f;  // 1/sqrt(128)
  const float NINF = -__builtin_inff();
  float ps[5][4];
  float mx0 = NINF, mx1 = NINF, mx2 = NINF, mx3 = NINF;
  #pragma unroll
  for (int n = 0; n < 5; ++n) {
    const bool ok = (n * 16 + (lane & 15)) < cnt;
    #pragma unroll
    for (int j = 0; j < 4; ++j) ps[n][j] = ok ? sc[n][j] * SCALE : NINF;
    mx0 = fmaxf(mx0, ps[n][0]); mx1 = fmaxf(mx1, ps[n][1]);
    mx2 = fmaxf(mx2, ps[n][2]); mx3 = fmaxf(mx3, ps[n][3]);
  }
  #pragma unroll
  for (int off = 1; off < 16; off <<= 1) {
    mx0 = fmaxf(mx0, __shfl_xor(mx0, off)); mx1 = fmaxf(mx1, __shfl_xor(mx1, off));
    mx2 = fmaxf(mx2, __shfl_xor(mx2, off)); mx3 = fmaxf(mx3, __shfl_xor(mx3, off));
  }
  float l0 = 0.f, l1 = 0.f, l2 = 0.f, l3 = 0.f;
  #pragma unroll
  for (int n = 0; n < 5; ++n) {
    ps[n][0] = __expf(ps[n][0] - mx0); l0 += ps[n][0];
    ps[n][1] = __expf(ps[n][1] - mx1); l1 += ps[n][1];
    ps[n][2] = __expf(ps[n][2] - mx2); l2 += ps[n][2];
    ps[n][3] = __expf(ps[n][3] - mx3); l3 += ps[n][3];
  }
  #pragma unroll
  for (int off = 1; off < 16; off <<= 1) {
    l0 += __shfl_xor(l0, off); l1 += __shfl_xor(l1, off);
    l2 += __shfl_xor(l2, off); l3 += __shfl_xor(l3, off);
  }
  const float i0 = 1.f / l0, i1 = 1.f / l1, i2 = 1.f / l2, i3 = 1.f / l3;
  if (lane < 16) {
    #pragma unroll
    for (int n = 0; n < 5; ++n) {
      const int key = n * 16 + lane;
      Pbuf[0 * 104 + key] = (f16)(ps[n][0] * i0);
      Pbuf[1 * 104 + key] = (f16)(ps[n][1] * i1);
      Pbuf[2 * 104 + key] = (f16)(ps[n][2] * i2);
      Pbuf[3 * 104 + key] = (f16)(ps[n][3] * i3);
    }
  }
  __syncthreads();  // all waves done with Kl; P complete

  // ---- phase 2.5: V regs -> Vt[128][104] (8-key-block XOR swizzle), aliases Kl
  #pragma unroll
  for (int it = 0; it < 6; ++it) {
    const int c = it * 256 + tid;
    const int r = c >> 4, ch = c & 15;
    #pragma unroll
    for (int e = 0; e < 8; ++e) {
      const int d = ch * 8 + e;
      const int rs = (r < 64) ? (r ^ (((d >> 3) & 7) << 3)) : r;
      KV[d * 104 + rs] = vreg[it][e];
    }
  }
  __syncthreads();  // Vt ready

  // ---- phase 3: PV (6 MFMA; wave owns dims 32w..32w+31), write O
  f32x4 ov0 = {0.f, 0.f, 0.f, 0.f}, ov1 = {0.f, 0.f, 0.f, 0.f};
  #pragma unroll
  for (int k0 = 0; k0 < 3; ++k0) {
    f16x8 pa = *(const f16x8*)&Pbuf[(lane & 15) * 104 + k0 * 32 + (lane >> 4) * 8];
    const int g = k0 * 4 + (lane >> 4);  // 8-key block index
    const int rbase = g * 8;
    {
      const int d = wave * 32 + (lane & 15);
      const int rs = (rbase < 64) ? (rbase ^ (((d >> 3) & 7) << 3)) : rbase;
      f16x8 vb = *(const f16x8*)&KV[d * 104 + rs];
      ov0 = __builtin_amdgcn_mfma_f32_16x16x32_f16(pa, vb, ov0, 0, 0, 0);
    }
    {
      const int d = wave * 32 + 16 + (lane & 15);
      const int rs = (rbase < 64) ? (rbase ^ (((d >> 3) & 7) << 3)) : rbase;
      f16x8 vb = *(const f16x8*)&KV[d * 104 + rs];
      ov1 = __builtin_amdgcn_mfma_f32_16x16x32_f16(pa, vb, ov1, 0, 0, 0);
    }
  }
  if (lane < 16) {
    const size_t yb = (size_t)row * 2048 + 4 * kvh * 128;
    #pragma unroll
    for (int j = 0; j < 4; ++j) {
      y[yb + j * 128 + wave * 32 + lane] = (f16)ov0[j];
      y[yb + j * 128 + wave * 32 + 16 + lane] = (f16)ov1[j];
    }
  }
}

// ================================================================ launch
extern "C" void kernel_launch(void* const* d_in, const int* in_sizes, int n_in,
                              void* d_out, int out_size, void* d_ws, size_t ws_size,
                              hipStream_t stream)
{
  (void)in_sizes; (void)n_in; (void)out_size; (void)ws_size;
  const float* x   = (const float*)d_in[0];
  const float* Wq  = (const float*)d_in[1];
  const float* bq  = (const float*)d_in[2];
  const float* Wkd = (const float*)d_in[3];
  const float* bkd = (const float*)d_in[4];
  const float* Wku = (const float*)d_in[5];
  const float* bku = (const float*)d_in[6];
  const float* Wo  = (const float*)d_in[7];
  const float* bo  = (const float*)d_in[8];
  float* out = (float*)d_out;

  char* ws = (char*)d_ws;
  size_t o = 0;
  auto alloc = [&](size_t bytes) -> void* {
    o = (o + 255) & ~(size_t)255;
    void* p = ws + o;
    o += bytes;
    return p;
  };
  f16* WqT   = (f16*)alloc(2048ull * 2048 * 2);
  f16* WoT   = (f16*)alloc(2048ull * 2048 * 2);
  f16* WkdT  = (f16*)alloc(512ull * 2048 * 2);
  f16* WkuT  = (f16*)alloc(1024ull * 512 * 2);
  f16* xh    = (f16*)alloc(4096ull * 2048 * 2);
  f16* qmain = (f16*)alloc(4096ull * 2048 * 2);  // reused as y after rope
  f16* kvh_  = (f16*)alloc(4096ull * 1024 * 2);
  f16* cbf   = (f16*)alloc(4096ull * 512 * 2);
  float* rc  = (float*)alloc(2048ull * 64 * 4);
  float* rs  = (float*)alloc(2048ull * 64 * 4);
  f16* qrope = (f16*)alloc(4096ull * 2048 * 2);
  f16* krope = (f16*)alloc(4096ull * 512 * 2);
  f16* vbf   = (f16*)alloc(4096ull * 512 * 2);
  int* selcnt = (int*)alloc(4096ull * 4);
  int* selidx = (int*)alloc(4096ull * 68 * 4);
  double* Bsel = (double*)alloc(2048ull * 128 * 8);
  double* bsel = (double*)alloc(128 * 8);
  double* qs64 = (double*)alloc(4096ull * 64 * 8);
  double* ks64 = (double*)alloc(4096ull * 64 * 8);
  double* ksT  = (double*)alloc(2ull * 64 * 2048 * 8);
  f16* yh = qmain;                   // alias: qmain dead after k_rope_q
  double* partial = (double*)qrope;  // alias: 16 MiB, dead until k_rope_q writes qrope

  // --- weight prep ---
  k_transpose_cast<<<dim3(64, 64), 256, 0, stream>>>(Wq, WqT, 2048, 2048);
  k_transpose_cast<<<dim3(16, 64), 256, 0, stream>>>(Wkd, WkdT, 2048, 512);
  k_transpose_cast<<<dim3(32, 16), 256, 0, stream>>>(Wku, WkuT, 512, 1024);
  k_transpose_cast<<<dim3(64, 64), 256, 0, stream>>>(Wo, WoT, 2048, 2048);
  k_cast_f16<<<8192, 256, 0, stream>>>(x, xh, 2097152);

  // --- fp64 selector path (split-K) ---
  k_prep_sel<<<2048, 64, 0, stream>>>(Wq, Wkd, Wku, Bsel);
  k_bias_sel<<<1, 128, 0, stream>>>(bq, bkd, Wku, bku, bsel);
  k_gemm_sel_f64<<<dim3(128, 2, 4), 256, 0, stream>>>(x, Bsel, partial);
  k_sel_reduce<<<2048, 256, 0, stream>>>(partial, bsel, qs64, ks64);
  k_transpose64<<<dim3(2, 64, 2), 256, 0, stream>>>(ks64, ksT);

  // --- fp16 MFMA main path ---
  k_gemm_bt<true><<<dim3(32, 16), 256, 0, stream>>>(xh, WqT, bq, nullptr, qmain,
                                                    4096, 2048, 2048, 2048, 2048, 2048);
  k_gemm_bt<true><<<dim3(32, 4), 256, 0, stream>>>(xh, WkdT, bkd, nullptr, cbf,
                                                   4096, 512, 2048, 2048, 2048, 512);
  k_gemm_bt<true><<<dim3(32, 8), 256, 0, stream>>>(cbf, WkuT, bku, nullptr, kvh_,
                                                   4096, 1024, 512, 512, 512, 1024);

  // --- RoPE (k_rope_q overwrites qrope AFTER k_sel_reduce consumed the alias) ---
  k_rope_table<<<2048, 64, 0, stream>>>(rc, rs);
  k_rope_q<<<16384, 256, 0, stream>>>(qmain, rc, rs, qrope);
  k_rope_kv<<<4096, 256, 0, stream>>>(kvh_, rc, rs, krope, vbf);

  // --- selector top-k ---
  k_topk64<<<2048, 256, 0, stream>>>(qs64, ksT, selcnt, selidx);

  // --- sparse attention (MFMA) ---
  k_attn<<<16384, 256, 0, stream>>>(qrope, krope, vbf, selcnt, selidx, yh);

  // --- output projection ---
  k_gemm_bt<false><<<dim3(32, 16), 256, 0, stream>>>(yh, WoT, bo, out, nullptr,
                                                     4096, 2048, 2048, 2048, 2048, 2048);
}

// Round 10
// 547.061 us; speedup vs baseline: 1.0809x; 1.0809x over previous
//
#include <hip/hip_runtime.h>

typedef unsigned int u32;
typedef unsigned long long u64;
typedef _Float16 f16;
typedef __attribute__((ext_vector_type(2))) _Float16 f16x2;
typedef __attribute__((ext_vector_type(4))) _Float16 f16x4;
typedef __attribute__((ext_vector_type(8))) _Float16 f16x8;
typedef __attribute__((ext_vector_type(4))) float f32x4;
typedef __attribute__((ext_vector_type(2))) double f64x2;

// Problem constants: B=2, T=2048, D=2048, LAT=512, H=16, HD=128, NKV=4, G=4,
// SEL_DIM=64, TOPK=64, NROW = 4096

// su storage swizzle: spreads the tid*8+e LDS sweep across 16 banks.
__device__ __forceinline__ int suX(int jj) { return jj ^ ((jj >> 4) & 7); }

// ------------------------------------------------- transpose + cast f32->f16
__global__ __launch_bounds__(256) void k_transpose_cast(const float* __restrict__ in,
                                                        f16* __restrict__ out, int R, int C)
{
  __shared__ float tile[32][33];
  int c0 = blockIdx.x * 32, r0 = blockIdx.y * 32;
  int tx = threadIdx.x & 31, ty = threadIdx.x >> 5;  // ty 0..7
  #pragma unroll
  for (int i = ty; i < 32; i += 8) tile[i][tx] = in[(size_t)(r0 + i) * C + c0 + tx];
  __syncthreads();
  #pragma unroll
  for (int i = ty; i < 32; i += 8) out[(size_t)(c0 + i) * R + r0 + tx] = (f16)tile[tx][i];
}

// ------------------------------------------------------------- cast f32->f16
__global__ __launch_bounds__(256) void k_cast_f16(const float* __restrict__ in,
                                                  f16* __restrict__ out, int n4)
{
  int i = blockIdx.x * 256 + threadIdx.x;
  if (i >= n4) return;
  f32x4 v = *(const f32x4*)&in[(size_t)i * 4];
  f16x4 h; h.x = (f16)v.x; h.y = (f16)v.y; h.z = (f16)v.z; h.w = (f16)v.w;
  *(f16x4*)&out[(size_t)i * 4] = h;
}

// ------------------------------------------------------------- fp64 selector weights
__global__ void k_prep_sel(const float* __restrict__ Wq, const float* __restrict__ Wkd,
                           const float* __restrict__ Wku, double* __restrict__ Bsel)
{
  const int k = blockIdx.x;   // 0..2047
  const int j = threadIdx.x;  // 0..63
  Bsel[(size_t)k * 128 + j] = (double)Wq[(size_t)k * 2048 + j];
  double s = 0.0;
  for (int l = 0; l < 512; ++l)
    s = fma((double)Wkd[(size_t)k * 512 + l], (double)Wku[(size_t)l * 1024 + j], s);
  Bsel[(size_t)k * 128 + 64 + j] = s;
}

__global__ void k_bias_sel(const float* __restrict__ bq, const float* __restrict__ bkd,
                           const float* __restrict__ Wku, const float* __restrict__ bku,
                           double* __restrict__ bsel)
{
  int j = threadIdx.x;  // 0..127
  if (j < 64) {
    bsel[j] = (double)bq[j];
  } else {
    int jj = j - 64;
    double s = (double)bku[jj];
    for (int l = 0; l < 512; ++l)
      s = fma((double)bkd[l], (double)Wku[(size_t)l * 1024 + jj], s);
    bsel[j] = s;
  }
}

// ------------------------------------------------------------- fp64 selector GEMM, split-K
__global__ __launch_bounds__(256) void k_gemm_sel_f64(const float* __restrict__ A,
                                                      const double* __restrict__ Bsel,
                                                      double* __restrict__ partial)
{
  __shared__ double As[32][33];
  __shared__ double Bs[32][66];
  const int m0 = blockIdx.x * 32, n0 = blockIdx.y * 64;
  const int kbase = blockIdx.z * 512, kend = kbase + 512;
  const int tid = threadIdx.x;
  const int tx = tid & 15, ty = tid >> 4;
  const int ar = tid >> 3, ac4 = (tid & 7) * 4;
  double acc[2][4] = {};

  f32x4 aN = *(const f32x4*)&A[(size_t)(m0 + ar) * 2048 + kbase + ac4];
  f64x2 bN[4];
  #pragma unroll
  for (int it = 0; it < 4; ++it) {
    int c = it * 256 + tid; int kk = c >> 5, n2 = (c & 31) * 2;
    bN[it] = *(const f64x2*)&Bsel[(size_t)(kbase + kk) * 128 + n0 + n2];
  }
  for (int k0 = kbase; k0 < kend; k0 += 32) {
    __syncthreads();
    As[ar][ac4] = (double)aN.x; As[ar][ac4 + 1] = (double)aN.y;
    As[ar][ac4 + 2] = (double)aN.z; As[ar][ac4 + 3] = (double)aN.w;
    #pragma unroll
    for (int it = 0; it < 4; ++it) {
      int c = it * 256 + tid; int kk = c >> 5, n2 = (c & 31) * 2;
      Bs[kk][n2] = bN[it].x; Bs[kk][n2 + 1] = bN[it].y;
    }
    __syncthreads();
    if (k0 + 32 < kend) {
      aN = *(const f32x4*)&A[(size_t)(m0 + ar) * 2048 + k0 + 32 + ac4];
      #pragma unroll
      for (int it = 0; it < 4; ++it) {
        int c = it * 256 + tid; int kk = c >> 5, n2 = (c & 31) * 2;
        bN[it] = *(const f64x2*)&Bsel[(size_t)(k0 + 32 + kk) * 128 + n0 + n2];
      }
    }
    #pragma unroll
    for (int kk = 0; kk < 32; ++kk) {
      double a0 = As[ty * 2][kk], a1 = As[ty * 2 + 1][kk];
      f64x2 b01 = *(const f64x2*)&Bs[kk][tx * 4];
      f64x2 b23 = *(const f64x2*)&Bs[kk][tx * 4 + 2];
      acc[0][0] = fma(a0, b01.x, acc[0][0]); acc[0][1] = fma(a0, b01.y, acc[0][1]);
      acc[0][2] = fma(a0, b23.x, acc[0][2]); acc[0][3] = fma(a0, b23.y, acc[0][3]);
      acc[1][0] = fma(a1, b01.x, acc[1][0]); acc[1][1] = fma(a1, b01.y, acc[1][1]);
      acc[1][2] = fma(a1, b23.x, acc[1][2]); acc[1][3] = fma(a1, b23.y, acc[1][3]);
    }
  }
  double* op = partial + (size_t)blockIdx.z * 4096 * 128;
  #pragma unroll
  for (int i = 0; i < 2; ++i) {
    int row = m0 + ty * 2 + i;
    #pragma unroll
    for (int j = 0; j < 4; ++j) {
      int n = n0 + tx * 4 + j;
      op[(size_t)row * 128 + n] = acc[i][j];
    }
  }
}

// Stage 2: fixed-order reduction of the 4 K-slice partials + bias.
__global__ __launch_bounds__(256) void k_sel_reduce(const double* __restrict__ partial,
                                                    const double* __restrict__ bias,
                                                    double* __restrict__ qs64,
                                                    double* __restrict__ ks64)
{
  const int idx = blockIdx.x * 256 + threadIdx.x;  // 0 .. 4096*128-1
  const int row = idx >> 7, n = idx & 127;
  const size_t S = 4096 * 128;
  double v = ((partial[idx] + partial[S + idx]) + partial[2 * S + idx]) + partial[3 * S + idx];
  v += bias[n];
  if (n < 64) qs64[(size_t)row * 64 + n] = v;
  else        ks64[(size_t)row * 64 + (n - 64)] = v;
}

// ------------------------------------------------------------- fp64 transpose
__global__ __launch_bounds__(256) void k_transpose64(const double* __restrict__ in,
                                                     double* __restrict__ out)
{
  __shared__ double tile[32][33];
  const int bt = blockIdx.z;
  const int c0 = blockIdx.x * 32;
  const int r0 = blockIdx.y * 32;
  int tx = threadIdx.x & 31, ty = threadIdx.x >> 5;
  const double* ip = in + (size_t)bt * 2048 * 64;
  double* op = out + (size_t)bt * 64 * 2048;
  #pragma unroll
  for (int i = ty; i < 32; i += 8) tile[i][tx] = ip[(size_t)(r0 + i) * 64 + c0 + tx];
  __syncthreads();
  #pragma unroll
  for (int i = ty; i < 32; i += 8) op[(size_t)(c0 + i) * 2048 + r0 + tx] = tile[tx][i];
}

// ------------------------------------------------------------- fp16 MFMA GEMM (m97 structure)
// + T1 XCD-aware block swizzle: each XCD gets a contiguous tile chunk -> B-panel
// L2 locality. Bijective (all grids here have nwg % 8 == 0).
template <bool OUTF16>
__global__ __launch_bounds__(256) void k_gemm_bt(const f16* __restrict__ A,
                                                 const f16* __restrict__ BT,
                                                 const float* __restrict__ bias,
                                                 float* __restrict__ C, f16* __restrict__ Ch,
                                                 int M, int N, int K, int lda, int ldb, int ldc)
{
  __shared__ __align__(16) f16 As[128 * 64];
  __shared__ __align__(16) f16 Bs[128 * 64];
  const int tid = threadIdx.x;
  const int lane = tid & 63;
  const int wave = tid >> 6;
  int bx = blockIdx.x, by = blockIdx.y;
  {
    const int nwg = gridDim.x * gridDim.y;
    if ((nwg & 7) == 0) {
      const int bid = by * gridDim.x + bx;
      const int cpx = nwg >> 3;
      const int sbid = (bid & 7) * cpx + (bid >> 3);
      bx = sbid % gridDim.x;
      by = sbid / gridDim.x;
    }
  }
  const int m0 = bx * 128, n0 = by * 128;
  const int wr = (wave >> 1) * 64, wc = (wave & 1) * 64;
  const int lrow = lane & 15;
  const int kgrp = (lane >> 4) * 8;
  f32x4 acc[4][4] = {};

  for (int k0 = 0; k0 < K; k0 += 64) {
    __syncthreads();
    #pragma unroll
    for (int it = 0; it < 4; ++it) {
      int c = it * 256 + tid;
      int r = c >> 3, c8 = (c & 7) * 8;
      int lbase = (it * 256 + (tid & 192)) * 8;  // wave-uniform LDS offset
      const f16* ga = A + (size_t)(m0 + r) * lda + k0 + c8;
      __builtin_amdgcn_global_load_lds((const __attribute__((address_space(1))) u32*)ga,
                                       (__attribute__((address_space(3))) u32*)&As[lbase],
                                       16, 0, 0);
      const f16* gb = BT + (size_t)(n0 + r) * ldb + k0 + c8;
      __builtin_amdgcn_global_load_lds((const __attribute__((address_space(1))) u32*)gb,
                                       (__attribute__((address_space(3))) u32*)&Bs[lbase],
                                       16, 0, 0);
    }
    __syncthreads();
    #pragma unroll
    for (int ks = 0; ks < 2; ++ks) {
      f16x8 af[4], bfr[4];
      #pragma unroll
      for (int m = 0; m < 4; ++m)
        af[m] = *(const f16x8*)&As[(wr + m * 16 + lrow) * 64 + ks * 32 + kgrp];
      #pragma unroll
      for (int n = 0; n < 4; ++n)
        bfr[n] = *(const f16x8*)&Bs[(wc + n * 16 + lrow) * 64 + ks * 32 + kgrp];
      #pragma unroll
      for (int m = 0; m < 4; ++m)
        #pragma unroll
        for (int n = 0; n < 4; ++n)
          acc[m][n] = __builtin_amdgcn_mfma_f32_16x16x32_f16(af[m], bfr[n], acc[m][n], 0, 0, 0);
    }
  }
  const int rbase = m0 + wr + (lane >> 4) * 4;  // C/D: col=lane&15, row=(lane>>4)*4+reg [m89]
  #pragma unroll
  for (int n = 0; n < 4; ++n) {
    int col = n0 + wc + n * 16 + lrow;
    float bv = bias ? bias[col] : 0.0f;
    #pragma unroll
    for (int m = 0; m < 4; ++m) {
      #pragma unroll
      for (int j = 0; j < 4; ++j) {
        int rowi = rbase + m * 16 + j;
        float v = acc[m][n][j] + bv;
        if (OUTF16) Ch[(size_t)rowi * ldc + col] = (f16)v;
        else        C[(size_t)rowi * ldc + col] = v;
      }
    }
  }
}

// ------------------------------------------------------------- RoPE tables
__global__ void k_rope_table(float* __restrict__ rc, float* __restrict__ rs)
{
  int t = blockIdx.x, i = threadIdx.x;  // 2048 x 64
  int fi = (2 * i) & 63;
  double inv = pow(10000.0, -(double)fi / 64.0);
  double a = (double)t * inv;
  rc[t * 64 + i] = (float)cos(a);
  rs[t * 64 + i] = (float)sin(a);
}

__global__ __launch_bounds__(256) void k_rope_q(const f16* __restrict__ q,
                                                const float* __restrict__ rc,
                                                const float* __restrict__ rs,
                                                f16* __restrict__ out)
{
  int g = blockIdx.x * 256 + threadIdx.x;  // 4096*16*64
  int row = g >> 10, rem = g & 1023;
  int h = rem >> 6, i = rem & 63;
  int t = row & 2047;
  size_t base = (size_t)row * 2048 + h * 128 + 2 * i;
  f16x2 v = *(const f16x2*)&q[base];
  float x1 = (float)v.x, x2 = (float)v.y;
  float c = rc[t * 64 + i], s = rs[t * 64 + i];
  f16x2 o; o.x = (f16)(x1 * c - x2 * s); o.y = (f16)(x1 * s + x2 * c);
  *(f16x2*)&out[base] = o;
}

__global__ __launch_bounds__(256) void k_rope_kv(const f16* __restrict__ kv,
                                                 const float* __restrict__ rc,
                                                 const float* __restrict__ rs,
                                                 f16* __restrict__ kout, f16* __restrict__ vout)
{
  int g = blockIdx.x * 256 + threadIdx.x;  // 4096*4*64
  int row = g >> 8, rem = g & 255;
  int kvh = rem >> 6, i = rem & 63;
  int t = row & 2047;
  size_t kb = (size_t)row * 1024 + kvh * 128 + 2 * i;
  f16x2 kvp = *(const f16x2*)&kv[kb];
  float x1 = (float)kvp.x, x2 = (float)kvp.y;
  float c = rc[t * 64 + i], s = rs[t * 64 + i];
  size_t ob = (size_t)row * 512 + kvh * 128 + 2 * i;
  f16x2 ko; ko.x = (f16)(x1 * c - x2 * s); ko.y = (f16)(x1 * s + x2 * c);
  *(f16x2*)&kout[ob] = ko;
  f16x2 vp = *(const f16x2*)&kv[(size_t)row * 1024 + 512 + kvh * 128 + 2 * i];
  *(f16x2*)&vout[ob] = vp;
}

// ------------------------------------------------------------- exact top-64, fp64 scores
__global__ __launch_bounds__(256) void k_topk64(const double* __restrict__ qs,
                                                const double* __restrict__ ksT,
                                                int* __restrict__ selcnt,
                                                int* __restrict__ selidx)
{
  const int r0 = blockIdx.x * 2;
  const int b = r0 >> 11;
  const int t0 = r0 & 2047, t1 = t0 + 1;
  const int tid = threadIdx.x;
  if (t1 < 64) {
    for (int lr = 0; lr < 2; ++lr) {
      int t = t0 + lr;
      int* outp = selidx + (size_t)(r0 + lr) * 68;
      for (int jj = tid; jj <= t; jj += 256) outp[jj] = jj;
      if (tid == 0) selcnt[r0 + lr] = t + 1;
    }
    return;
  }
  __shared__ double qrowP[64][2];
  __shared__ u64 su[2][2048];
  __shared__ unsigned hist[256], sA[256], sB[256];
  __shared__ unsigned s_bsel, s_larger, s_cnt;
  __shared__ u64 s_thr;
  __shared__ int s_remfin;
  __shared__ int cand[128];
  __shared__ u64 ckey[128];

  if (tid < 128) qrowP[tid >> 1][tid & 1] = qs[(size_t)(r0 + (tid & 1)) * 64 + (tid >> 1)];
  __syncthreads();
  {
    const double* kb = ksT + (size_t)b * 64 * 2048;
    const int emax = t1 >> 8;
    for (int e = 0; e <= emax; ++e) {
      const int jj = e * 256 + tid;
      double acc0 = 0.0, acc1 = 0.0;
      const double* kp = kb + jj;
      #pragma unroll 16
      for (int d = 0; d < 64; ++d) {
        double kv = kp[(size_t)d * 2048];
        f64x2 qp = *(const f64x2*)&qrowP[d][0];
        acc0 = fma(qp.x, kv, acc0);
        acc1 = fma(qp.y, kv, acc1);
      }
      const int sx = suX(jj);
      u64 u0 = (u64)__double_as_longlong(acc0);
      su[0][sx] = (u0 >> 63) ? ~u0 : (u0 | 0x8000000000000000ull);
      u64 u1 = (u64)__double_as_longlong(acc1);
      su[1][sx] = (u1 >> 63) ? ~u1 : (u1 | 0x8000000000000000ull);
    }
  }
  __syncthreads();

  const int c0 = tid * 8;
  for (int lr = 0; lr < 2; ++lr) {
    const int t = t0 + lr;
    int* outp = selidx + (size_t)(r0 + lr) * 68;
    const u64* S = su[lr];
    u64 prefix = 0;
    int remaining = 64;
    int broke = 0, sh_final = 0;
    for (int byte = 7; byte >= 0; --byte) {
      const int sh = byte * 8;
      hist[tid] = 0;
      __syncthreads();
      {
        unsigned bn[8]; bool vl[8];
        #pragma unroll
        for (int e = 0; e < 8; ++e) {
          int jj = c0 + e;
          u64 u = (jj <= t) ? S[suX(jj)] : 0;
          bool ok = (jj <= t) && ((byte == 7) || (((u ^ prefix) >> (sh + 8)) == 0));
          bn[e] = (unsigned)((u >> sh) & 255);
          vl[e] = ok;
        }
        #pragma unroll
        for (int e = 0; e < 8; ++e) {
          if (vl[e]) {
            bool first = true;
            #pragma unroll
            for (int p = 0; p < 8; ++p)
              if (p < e && vl[p] && bn[p] == bn[e]) first = false;
            if (first) {
              unsigned c = 0;
              #pragma unroll
              for (int q = 0; q < 8; ++q)
                if (q >= e && vl[q] && bn[q] == bn[e]) ++c;
              atomicAdd(&hist[bn[e]], c);
            }
          }
        }
      }
      __syncthreads();
      unsigned* sp = sA; unsigned* dp = sB;
      sp[tid] = hist[tid];
      __syncthreads();
      #pragma unroll
      for (int off = 1; off < 256; off <<= 1) {
        dp[tid] = sp[tid] + ((tid + off < 256) ? sp[tid + off] : 0u);
        __syncthreads();
        unsigned* tpp = sp; sp = dp; dp = tpp;
      }
      unsigned inc = sp[tid];
      unsigned cumAbove = (tid == 255) ? 0u : sp[tid + 1];
      if ((int)cumAbove < remaining && (int)inc >= remaining) {
        s_bsel = (unsigned)tid;
        s_larger = cumAbove;
        s_cnt = inc - cumAbove;
      }
      __syncthreads();
      prefix |= ((u64)s_bsel << sh);
      remaining -= (int)s_larger;
      int cnt = (int)s_cnt;
      __syncthreads();
      if (cnt <= 128) { broke = 1; sh_final = sh; break; }
    }
    u64 thr;
    int remfin;
    if (broke) {
      unsigned cg = 0;
      #pragma unroll
      for (int e = 0; e < 8; ++e) {
        int jj = c0 + e;
        if (jj <= t && (((S[suX(jj)] ^ prefix) >> sh_final) == 0)) ++cg;
      }
      unsigned* sp = sA; unsigned* dp = sB;
      sp[tid] = cg;
      __syncthreads();
      #pragma unroll
      for (int off = 1; off < 256; off <<= 1) {
        dp[tid] = sp[tid] + ((tid >= off) ? sp[tid - off] : 0u);
        __syncthreads();
        unsigned* tpp = sp; sp = dp; dp = tpp;
      }
      const int C = (int)sp[255];
      int pos = (int)(sp[tid] - cg);
      #pragma unroll
      for (int e = 0; e < 8; ++e) {
        int jj = c0 + e;
        if (jj <= t && (((S[suX(jj)] ^ prefix) >> sh_final) == 0)) cand[pos++] = jj;
      }
      __syncthreads();
      if (tid < C) ckey[tid] = S[suX(cand[tid])];
      __syncthreads();
      if (tid < C) {
        u64 k = ckey[tid];
        int g = 0, eq = 0;
        for (int j = 0; j < C; ++j) {
          g += (ckey[j] > k) ? 1 : 0;
          eq += (ckey[j] == k) ? 1 : 0;
        }
        if (g < remaining && remaining <= g + eq) {
          s_thr = k;
          s_remfin = remaining - g;
        }
      }
      __syncthreads();
      thr = s_thr;
      remfin = s_remfin;
    } else {
      thr = prefix;
      remfin = remaining;
    }
    __syncthreads();
    unsigned cg = 0, ct_ = 0;
    #pragma unroll
    for (int e = 0; e < 8; ++e) {
      int jj = c0 + e;
      if (jj <= t) {
        u64 u = S[suX(jj)];
        cg += (u > thr) ? 1u : 0u;
        ct_ += (u == thr) ? 1u : 0u;
      }
    }
    const unsigned pack = cg | (ct_ << 16);
    {
      unsigned* sp = sA; unsigned* dp = sB;
      sp[tid] = pack;
      __syncthreads();
      #pragma unroll
      for (int off = 1; off < 256; off <<= 1) {
        dp[tid] = sp[tid] + ((tid >= off) ? sp[tid - off] : 0u);
        __syncthreads();
        unsigned* tpp = sp; sp = dp; dp = tpp;
      }
      const unsigned excl = sp[tid] - pack;
      const unsigned tot = sp[255];
      const unsigned Gtot = tot & 0xFFFFu;
      const u64 ut = S[suX(t)];
      const unsigned gt = (ut > thr) ? 1u : 0u;
      const unsigned tt = (ut == thr) ? 1u : 0u;
      const int GtotX = (int)(Gtot - gt);
      int gpos = (int)(excl & 0xFFFFu);
      int tpos = (int)(excl >> 16);
      #pragma unroll
      for (int e = 0; e < 8; ++e) {
        int jj = c0 + e;
        if (jj > t) break;
        u64 u = S[suX(jj)];
        if (u > thr) {
          if (jj != t) outp[1 + gpos] = jj;
          ++gpos;
        } else if (u == thr) {
          if (jj != t && tpos < remfin) outp[1 + GtotX + tpos] = jj;
          ++tpos;
        }
      }
      if (tid == 0) {
        outp[0] = t;
        const unsigned Ttot = tot >> 16;
        int tb = (int)(Ttot - tt);
        int emitT = tb < remfin ? tb : remfin;
        selcnt[r0 + lr] = 1 + GtotX + emitT;  // 64 or 65
      }
    }
    __syncthreads();
  }
}

// ------------------------------------------------------------- sparse attention
// R8's proven LDS-staged fdot2 version (R9's MFMA rewrite regressed: 38M bank
// conflicts + equal VALU work). One change: PV unrolled x4 with f32x4 p-broadcast
// reads; Vl/pl padded to 68 and tail-zeroed so unrolled tail reads are finite.
// Summation order identical to R8.
__global__ __launch_bounds__(256) void k_attn(const f16* __restrict__ qr,
                                              const f16* __restrict__ kr,
                                              const f16* __restrict__ vv,
                                              const int* __restrict__ selcnt,
                                              const int* __restrict__ selidx,
                                              f16* __restrict__ y)
{
  const int blk = blockIdx.x;  // row*4 + kvh
  const int row = blk >> 2, kvh = blk & 3;
  const int b = row >> 11;
  const int tid = threadIdx.x, lane = tid & 63, wave = tid >> 6;
  const int cnt = selcnt[row];
  __shared__ int sidx[68];
  __shared__ __align__(16) f16 Kl[65 * 128];   // chunk-XOR swizzled
  __shared__ __align__(16) f16 Vl[68 * 128];   // linear, rows [cnt,68) zeroed
  __shared__ f16 qlds[4][128];
  __shared__ __align__(16) float pl[4][68];    // [cnt..68) zeroed
  if (tid < cnt) sidx[tid] = selidx[(size_t)row * 68 + tid];
  *(f16x2*)&qlds[wave][lane * 2] =
      *(const f16x2*)&qr[((size_t)row * 16 + kvh * 4 + wave) * 128 + lane * 2];
  __syncthreads();  // sidx ready

  const int nch = cnt * 16;
  for (int c = tid; c < nch; c += 256) {
    const int r = c >> 4, ch = c & 15;
    const size_t kbase = ((size_t)(b * 2048 + sidx[r])) * 512 + kvh * 128 + ch * 8;
    f16x8 k8 = *(const f16x8*)&kr[kbase];
    *(f16x8*)&Kl[r * 128 + ((ch ^ (r & 15)) * 8)] = k8;
    f16x8 v8 = *(const f16x8*)&vv[kbase];
    *(f16x8*)&Vl[r * 128 + ch * 8] = v8;
  }
  // zero Vl rows [cnt, 68)
  for (int i = tid; i < (68 - cnt) * 64; i += 256)
    ((u32*)Vl)[cnt * 64 + i] = 0u;
  __syncthreads();

  const float SCALE = 0.08838834764831845f;  // 1/sqrt(128)
  auto dotk = [&](int r) -> float {
    const int sw = r & 15;
    float s = 0.0f;
    #pragma unroll
    for (int i = 0; i < 16; ++i) {
      f16x8 k8 = *(const f16x8*)&Kl[r * 128 + ((i ^ sw) * 8)];
      f16x8 q8 = *(const f16x8*)&qlds[wave][i * 8];
      #pragma unroll
      for (int e = 0; e < 4; ++e) {
        f16x2 ka; ka.x = k8[2 * e]; ka.y = k8[2 * e + 1];
        f16x2 qa; qa.x = q8[2 * e]; qa.y = q8[2 * e + 1];
        s = __builtin_amdgcn_fdot2(ka, qa, s, false);
      }
    }
    return s * SCALE;
  };

  float s1 = -__builtin_inff(), s2 = -__builtin_inff();
  if (lane < cnt) s1 = dotk(lane);
  if (lane + 64 < cnt) s2 = dotk(lane + 64);  // only lane 0, cnt==65
  float mx = fmaxf(s1, s2);
  #pragma unroll
  for (int off = 32; off; off >>= 1) mx = fmaxf(mx, __shfl_xor(mx, off));
  float p1 = (lane < cnt) ? __expf(s1 - mx) : 0.0f;
  float p2 = (lane + 64 < cnt) ? __expf(s2 - mx) : 0.0f;
  float l = p1 + p2;
  #pragma unroll
  for (int off = 32; off; off >>= 1) l += __shfl_xor(l, off);
  float linv = 1.0f / l;
  pl[wave][lane] = p1;
  if (lane == 0) pl[wave][64] = p2;
  if (lane < 3) pl[wave][65 + lane] = 0.0f;
  __syncthreads();

  float y0 = 0.0f, y1 = 0.0f;
  const int d2 = lane * 2;
  for (int j = 0; j < cnt; j += 4) {
    f32x4 p4 = *(const f32x4*)&pl[wave][j];
    f16x2 va = *(const f16x2*)&Vl[(j + 0) * 128 + d2];
    f16x2 vb = *(const f16x2*)&Vl[(j + 1) * 128 + d2];
    f16x2 vc = *(const f16x2*)&Vl[(j + 2) * 128 + d2];
    f16x2 vd = *(const f16x2*)&Vl[(j + 3) * 128 + d2];
    y0 = fmaf(p4.x, (float)va.x, y0); y1 = fmaf(p4.x, (float)va.y, y1);
    y0 = fmaf(p4.y, (float)vb.x, y0); y1 = fmaf(p4.y, (float)vb.y, y1);
    y0 = fmaf(p4.z, (float)vc.x, y0); y1 = fmaf(p4.z, (float)vc.y, y1);
    y0 = fmaf(p4.w, (float)vd.x, y0); y1 = fmaf(p4.w, (float)vd.y, y1);
  }
  y0 *= linv; y1 *= linv;
  f16x2 o; o.x = (f16)y0; o.y = (f16)y1;
  *(f16x2*)&y[(size_t)row * 2048 + (kvh * 4 + wave) * 128 + d2] = o;
}

// ================================================================ launch
extern "C" void kernel_launch(void* const* d_in, const int* in_sizes, int n_in,
                              void* d_out, int out_size, void* d_ws, size_t ws_size,
                              hipStream_t stream)
{
  (void)in_sizes; (void)n_in; (void)out_size; (void)ws_size;
  const float* x   = (const float*)d_in[0];
  const float* Wq  = (const float*)d_in[1];
  const float* bq  = (const float*)d_in[2];
  const float* Wkd = (const float*)d_in[3];
  const float* bkd = (const float*)d_in[4];
  const float* Wku = (const float*)d_in[5];
  const float* bku = (const float*)d_in[6];
  const float* Wo  = (const float*)d_in[7];
  const float* bo  = (const float*)d_in[8];
  float* out = (float*)d_out;

  char* ws = (char*)d_ws;
  size_t o = 0;
  auto alloc = [&](size_t bytes) -> void* {
    o = (o + 255) & ~(size_t)255;
    void* p = ws + o;
    o += bytes;
    return p;
  };
  f16* WqT   = (f16*)alloc(2048ull * 2048 * 2);
  f16* WoT   = (f16*)alloc(2048ull * 2048 * 2);
  f16* WkdT  = (f16*)alloc(512ull * 2048 * 2);
  f16* WkuT  = (f16*)alloc(1024ull * 512 * 2);
  f16* xh    = (f16*)alloc(4096ull * 2048 * 2);
  f16* qmain = (f16*)alloc(4096ull * 2048 * 2);  // reused as y after rope
  f16* kvh_  = (f16*)alloc(4096ull * 1024 * 2);
  f16* cbf   = (f16*)alloc(4096ull * 512 * 2);
  float* rc  = (float*)alloc(2048ull * 64 * 4);
  float* rs  = (float*)alloc(2048ull * 64 * 4);
  f16* qrope = (f16*)alloc(4096ull * 2048 * 2);
  f16* krope = (f16*)alloc(4096ull * 512 * 2);
  f16* vbf   = (f16*)alloc(4096ull * 512 * 2);
  int* selcnt = (int*)alloc(4096ull * 4);
  int* selidx = (int*)alloc(4096ull * 68 * 4);
  double* Bsel = (double*)alloc(2048ull * 128 * 8);
  double* bsel = (double*)alloc(128 * 8);
  double* qs64 = (double*)alloc(4096ull * 64 * 8);
  double* ks64 = (double*)alloc(4096ull * 64 * 8);
  double* ksT  = (double*)alloc(2ull * 64 * 2048 * 8);
  f16* yh = qmain;                   // alias: qmain dead after k_rope_q
  double* partial = (double*)qrope;  // alias: 16 MiB, dead until k_rope_q writes qrope

  // --- weight prep ---
  k_transpose_cast<<<dim3(64, 64), 256, 0, stream>>>(Wq, WqT, 2048, 2048);
  k_transpose_cast<<<dim3(16, 64), 256, 0, stream>>>(Wkd, WkdT, 2048, 512);
  k_transpose_cast<<<dim3(32, 16), 256, 0, stream>>>(Wku, WkuT, 512, 1024);
  k_transpose_cast<<<dim3(64, 64), 256, 0, stream>>>(Wo, WoT, 2048, 2048);
  k_cast_f16<<<8192, 256, 0, stream>>>(x, xh, 2097152);

  // --- fp64 selector path (split-K) ---
  k_prep_sel<<<2048, 64, 0, stream>>>(Wq, Wkd, Wku, Bsel);
  k_bias_sel<<<1, 128, 0, stream>>>(bq, bkd, Wku, bku, bsel);
  k_gemm_sel_f64<<<dim3(128, 2, 4), 256, 0, stream>>>(x, Bsel, partial);
  k_sel_reduce<<<2048, 256, 0, stream>>>(partial, bsel, qs64, ks64);
  k_transpose64<<<dim3(2, 64, 2), 256, 0, stream>>>(ks64, ksT);

  // --- fp16 MFMA main path (XCD-swizzled) ---
  k_gemm_bt<true><<<dim3(32, 16), 256, 0, stream>>>(xh, WqT, bq, nullptr, qmain,
                                                    4096, 2048, 2048, 2048, 2048, 2048);
  k_gemm_bt<true><<<dim3(32, 4), 256, 0, stream>>>(xh, WkdT, bkd, nullptr, cbf,
                                                   4096, 512, 2048, 2048, 2048, 512);
  k_gemm_bt<true><<<dim3(32, 8), 256, 0, stream>>>(cbf, WkuT, bku, nullptr, kvh_,
                                                   4096, 1024, 512, 512, 512, 1024);

  // --- RoPE (k_rope_q overwrites qrope AFTER k_sel_reduce consumed the alias) ---
  k_rope_table<<<2048, 64, 0, stream>>>(rc, rs);
  k_rope_q<<<16384, 256, 0, stream>>>(qmain, rc, rs, qrope);
  k_rope_kv<<<4096, 256, 0, stream>>>(kvh_, rc, rs, krope, vbf);

  // --- selector top-k ---
  k_topk64<<<2048, 256, 0, stream>>>(qs64, ksT, selcnt, selidx);

  // --- sparse attention ---
  k_attn<<<16384, 256, 0, stream>>>(qrope, krope, vbf, selcnt, selidx, yh);

  // --- output projection ---
  k_gemm_bt<false><<<dim3(32, 16), 256, 0, stream>>>(yh, WoT, bo, out, nullptr,
                                                     4096, 2048, 2048, 2048, 2048, 2048);
}

// Round 11
// 542.384 us; speedup vs baseline: 1.0902x; 1.0086x over previous
//
#include <hip/hip_runtime.h>

typedef unsigned int u32;
typedef unsigned long long u64;
typedef _Float16 f16;
typedef __attribute__((ext_vector_type(2))) _Float16 f16x2;
typedef __attribute__((ext_vector_type(4))) _Float16 f16x4;
typedef __attribute__((ext_vector_type(8))) _Float16 f16x8;
typedef __attribute__((ext_vector_type(4))) float f32x4;
typedef __attribute__((ext_vector_type(2))) double f64x2;

// Problem constants: B=2, T=2048, D=2048, LAT=512, H=16, HD=128, NKV=4, G=4,
// SEL_DIM=64, TOPK=64, NROW = 4096

// su storage swizzle: spreads the tid*8+e LDS sweep across 16 banks.
__device__ __forceinline__ int suX(int jj) { return jj ^ ((jj >> 4) & 7); }

// ------------------------------------------------- transpose + cast f32->f16
__global__ __launch_bounds__(256) void k_transpose_cast(const float* __restrict__ in,
                                                        f16* __restrict__ out, int R, int C)
{
  __shared__ float tile[32][33];
  int c0 = blockIdx.x * 32, r0 = blockIdx.y * 32;
  int tx = threadIdx.x & 31, ty = threadIdx.x >> 5;  // ty 0..7
  #pragma unroll
  for (int i = ty; i < 32; i += 8) tile[i][tx] = in[(size_t)(r0 + i) * C + c0 + tx];
  __syncthreads();
  #pragma unroll
  for (int i = ty; i < 32; i += 8) out[(size_t)(c0 + i) * R + r0 + tx] = (f16)tile[tx][i];
}

// ------------------------------------------------------------- cast f32->f16
__global__ __launch_bounds__(256) void k_cast_f16(const float* __restrict__ in,
                                                  f16* __restrict__ out, int n4)
{
  int i = blockIdx.x * 256 + threadIdx.x;
  if (i >= n4) return;
  f32x4 v = *(const f32x4*)&in[(size_t)i * 4];
  f16x4 h; h.x = (f16)v.x; h.y = (f16)v.y; h.z = (f16)v.z; h.w = (f16)v.w;
  *(f16x4*)&out[(size_t)i * 4] = h;
}

// ------------------------------------------------------------- fp64 selector weights
__global__ void k_prep_sel(const float* __restrict__ Wq, const float* __restrict__ Wkd,
                           const float* __restrict__ Wku, double* __restrict__ Bsel)
{
  const int k = blockIdx.x;   // 0..2047
  const int j = threadIdx.x;  // 0..63
  Bsel[(size_t)k * 128 + j] = (double)Wq[(size_t)k * 2048 + j];
  double s = 0.0;
  for (int l = 0; l < 512; ++l)
    s = fma((double)Wkd[(size_t)k * 512 + l], (double)Wku[(size_t)l * 1024 + j], s);
  Bsel[(size_t)k * 128 + 64 + j] = s;
}

__global__ void k_bias_sel(const float* __restrict__ bq, const float* __restrict__ bkd,
                           const float* __restrict__ Wku, const float* __restrict__ bku,
                           double* __restrict__ bsel)
{
  int j = threadIdx.x;  // 0..127
  if (j < 64) {
    bsel[j] = (double)bq[j];
  } else {
    int jj = j - 64;
    double s = (double)bku[jj];
    for (int l = 0; l < 512; ++l)
      s = fma((double)bkd[l], (double)Wku[(size_t)l * 1024 + jj], s);
    bsel[j] = s;
  }
}

// ------------------------------------------------------------- fp64 selector GEMM, split-K
__global__ __launch_bounds__(256) void k_gemm_sel_f64(const float* __restrict__ A,
                                                      const double* __restrict__ Bsel,
                                                      double* __restrict__ partial)
{
  __shared__ double As[32][33];
  __shared__ double Bs[32][66];
  const int m0 = blockIdx.x * 32, n0 = blockIdx.y * 64;
  const int kbase = blockIdx.z * 512, kend = kbase + 512;
  const int tid = threadIdx.x;
  const int tx = tid & 15, ty = tid >> 4;
  const int ar = tid >> 3, ac4 = (tid & 7) * 4;
  double acc[2][4] = {};

  f32x4 aN = *(const f32x4*)&A[(size_t)(m0 + ar) * 2048 + kbase + ac4];
  f64x2 bN[4];
  #pragma unroll
  for (int it = 0; it < 4; ++it) {
    int c = it * 256 + tid; int kk = c >> 5, n2 = (c & 31) * 2;
    bN[it] = *(const f64x2*)&Bsel[(size_t)(kbase + kk) * 128 + n0 + n2];
  }
  for (int k0 = kbase; k0 < kend; k0 += 32) {
    __syncthreads();
    As[ar][ac4] = (double)aN.x; As[ar][ac4 + 1] = (double)aN.y;
    As[ar][ac4 + 2] = (double)aN.z; As[ar][ac4 + 3] = (double)aN.w;
    #pragma unroll
    for (int it = 0; it < 4; ++it) {
      int c = it * 256 + tid; int kk = c >> 5, n2 = (c & 31) * 2;
      Bs[kk][n2] = bN[it].x; Bs[kk][n2 + 1] = bN[it].y;
    }
    __syncthreads();
    if (k0 + 32 < kend) {
      aN = *(const f32x4*)&A[(size_t)(m0 + ar) * 2048 + k0 + 32 + ac4];
      #pragma unroll
      for (int it = 0; it < 4; ++it) {
        int c = it * 256 + tid; int kk = c >> 5, n2 = (c & 31) * 2;
        bN[it] = *(const f64x2*)&Bsel[(size_t)(k0 + 32 + kk) * 128 + n0 + n2];
      }
    }
    #pragma unroll
    for (int kk = 0; kk < 32; ++kk) {
      double a0 = As[ty * 2][kk], a1 = As[ty * 2 + 1][kk];
      f64x2 b01 = *(const f64x2*)&Bs[kk][tx * 4];
      f64x2 b23 = *(const f64x2*)&Bs[kk][tx * 4 + 2];
      acc[0][0] = fma(a0, b01.x, acc[0][0]); acc[0][1] = fma(a0, b01.y, acc[0][1]);
      acc[0][2] = fma(a0, b23.x, acc[0][2]); acc[0][3] = fma(a0, b23.y, acc[0][3]);
      acc[1][0] = fma(a1, b01.x, acc[1][0]); acc[1][1] = fma(a1, b01.y, acc[1][1]);
      acc[1][2] = fma(a1, b23.x, acc[1][2]); acc[1][3] = fma(a1, b23.y, acc[1][3]);
    }
  }
  double* op = partial + (size_t)blockIdx.z * 4096 * 128;
  #pragma unroll
  for (int i = 0; i < 2; ++i) {
    int row = m0 + ty * 2 + i;
    #pragma unroll
    for (int j = 0; j < 4; ++j) {
      int n = n0 + tx * 4 + j;
      op[(size_t)row * 128 + n] = acc[i][j];
    }
  }
}

// Stage 2: fixed-order reduction of the 4 K-slice partials + bias.
__global__ __launch_bounds__(256) void k_sel_reduce(const double* __restrict__ partial,
                                                    const double* __restrict__ bias,
                                                    double* __restrict__ qs64,
                                                    double* __restrict__ ks64)
{
  const int idx = blockIdx.x * 256 + threadIdx.x;  // 0 .. 4096*128-1
  const int row = idx >> 7, n = idx & 127;
  const size_t S = 4096 * 128;
  double v = ((partial[idx] + partial[S + idx]) + partial[2 * S + idx]) + partial[3 * S + idx];
  v += bias[n];
  if (n < 64) qs64[(size_t)row * 64 + n] = v;
  else        ks64[(size_t)row * 64 + (n - 64)] = v;
}

// ------------------------------------------------------------- fp64 transpose
__global__ __launch_bounds__(256) void k_transpose64(const double* __restrict__ in,
                                                     double* __restrict__ out)
{
  __shared__ double tile[32][33];
  const int bt = blockIdx.z;
  const int c0 = blockIdx.x * 32;
  const int r0 = blockIdx.y * 32;
  int tx = threadIdx.x & 31, ty = threadIdx.x >> 5;
  const double* ip = in + (size_t)bt * 2048 * 64;
  double* op = out + (size_t)bt * 64 * 2048;
  #pragma unroll
  for (int i = ty; i < 32; i += 8) tile[i][tx] = ip[(size_t)(r0 + i) * 64 + c0 + tx];
  __syncthreads();
  #pragma unroll
  for (int i = ty; i < 32; i += 8) op[(size_t)(c0 + i) * 2048 + r0 + tx] = tile[tx][i];
}

// ------------------------------------------------------------- fp16 MFMA GEMM (m97 structure)
// MODE 0: f32 out + bias (Wo).  MODE 1: f16 out + bias (Wkd).
// MODE 2: fused RoPE-q epilogue -> f16 (Wq): pair partner lives in lane lrow^1,
//         fetched with shfl_xor(v,1); single rounding (better than R10's 2-step).
// MODE 3: fused RoPE-k / V-split epilogue (Wku): n0<512 tiles are K (rope->Kout),
//         n0>=512 tiles are V (copy->Vout).
template <int MODE>
__global__ __launch_bounds__(256) void k_gemm_bt(const f16* __restrict__ A,
                                                 const f16* __restrict__ BT,
                                                 const float* __restrict__ bias,
                                                 float* __restrict__ C, f16* __restrict__ Ch,
                                                 f16* __restrict__ Kout, f16* __restrict__ Vout,
                                                 const float* __restrict__ rc,
                                                 const float* __restrict__ rs,
                                                 int M, int N, int K, int lda, int ldb, int ldc)
{
  __shared__ __align__(16) f16 As[128 * 64];
  __shared__ __align__(16) f16 Bs[128 * 64];
  const int tid = threadIdx.x;
  const int lane = tid & 63;
  const int wave = tid >> 6;
  int bx = blockIdx.x, by = blockIdx.y;
  {
    const int nwg = gridDim.x * gridDim.y;
    if ((nwg & 7) == 0) {
      const int bid = by * gridDim.x + bx;
      const int cpx = nwg >> 3;
      const int sbid = (bid & 7) * cpx + (bid >> 3);
      bx = sbid % gridDim.x;
      by = sbid / gridDim.x;
    }
  }
  const int m0 = bx * 128, n0 = by * 128;
  const int wr = (wave >> 1) * 64, wc = (wave & 1) * 64;
  const int lrow = lane & 15;
  const int kgrp = (lane >> 4) * 8;
  f32x4 acc[4][4] = {};

  for (int k0 = 0; k0 < K; k0 += 64) {
    __syncthreads();
    #pragma unroll
    for (int it = 0; it < 4; ++it) {
      int c = it * 256 + tid;
      int r = c >> 3, c8 = (c & 7) * 8;
      int lbase = (it * 256 + (tid & 192)) * 8;  // wave-uniform LDS offset
      const f16* ga = A + (size_t)(m0 + r) * lda + k0 + c8;
      __builtin_amdgcn_global_load_lds((const __attribute__((address_space(1))) u32*)ga,
                                       (__attribute__((address_space(3))) u32*)&As[lbase],
                                       16, 0, 0);
      const f16* gb = BT + (size_t)(n0 + r) * ldb + k0 + c8;
      __builtin_amdgcn_global_load_lds((const __attribute__((address_space(1))) u32*)gb,
                                       (__attribute__((address_space(3))) u32*)&Bs[lbase],
                                       16, 0, 0);
    }
    __syncthreads();
    #pragma unroll
    for (int ks = 0; ks < 2; ++ks) {
      f16x8 af[4], bfr[4];
      #pragma unroll
      for (int m = 0; m < 4; ++m)
        af[m] = *(const f16x8*)&As[(wr + m * 16 + lrow) * 64 + ks * 32 + kgrp];
      #pragma unroll
      for (int n = 0; n < 4; ++n)
        bfr[n] = *(const f16x8*)&Bs[(wc + n * 16 + lrow) * 64 + ks * 32 + kgrp];
      #pragma unroll
      for (int m = 0; m < 4; ++m)
        #pragma unroll
        for (int n = 0; n < 4; ++n)
          acc[m][n] = __builtin_amdgcn_mfma_f32_16x16x32_f16(af[m], bfr[n], acc[m][n], 0, 0, 0);
    }
  }
  const int rbase = m0 + wr + (lane >> 4) * 4;  // C/D: col=lane&15, row=(lane>>4)*4+reg [m89]
  #pragma unroll
  for (int n = 0; n < 4; ++n) {
    int col = n0 + wc + n * 16 + lrow;
    float bv = bias ? bias[col] : 0.0f;
    const int ri = (col & 127) >> 1;  // rope pair index (MODE 2/3)
    #pragma unroll
    for (int m = 0; m < 4; ++m) {
      #pragma unroll
      for (int j = 0; j < 4; ++j) {
        int rowi = rbase + m * 16 + j;
        float v = acc[m][n][j] + bv;
        if (MODE == 0) {
          C[(size_t)rowi * ldc + col] = v;
        } else if (MODE == 1) {
          Ch[(size_t)rowi * ldc + col] = (f16)v;
        } else if (MODE == 2) {
          float vp = __shfl_xor(v, 1);
          int t = rowi & 2047;
          float c_ = rc[t * 64 + ri], s_ = rs[t * 64 + ri];
          float r_ = (lrow & 1) ? (vp * s_ + v * c_) : (v * c_ - vp * s_);
          Ch[(size_t)rowi * ldc + col] = (f16)r_;
        } else {  // MODE 3
          float vp = __shfl_xor(v, 1);
          if (n0 < 512) {  // K tile: rope
            int t = rowi & 2047;
            float c_ = rc[t * 64 + ri], s_ = rs[t * 64 + ri];
            float r_ = (lrow & 1) ? (vp * s_ + v * c_) : (v * c_ - vp * s_);
            Kout[(size_t)rowi * 512 + col] = (f16)r_;
          } else {         // V tile: copy
            Vout[(size_t)rowi * 512 + (col - 512)] = (f16)v;
          }
        }
      }
    }
  }
}

// ------------------------------------------------------------- RoPE tables
__global__ void k_rope_table(float* __restrict__ rc, float* __restrict__ rs)
{
  int t = blockIdx.x, i = threadIdx.x;  // 2048 x 64
  int fi = (2 * i) & 63;
  double inv = pow(10000.0, -(double)fi / 64.0);
  double a = (double)t * inv;
  rc[t * 64 + i] = (float)cos(a);
  rs[t * 64 + i] = (float)sin(a);
}

// ------------------------------------------------------------- exact top-64, fp64 scores
__global__ __launch_bounds__(256) void k_topk64(const double* __restrict__ qs,
                                                const double* __restrict__ ksT,
                                                int* __restrict__ selcnt,
                                                int* __restrict__ selidx)
{
  const int r0 = blockIdx.x * 2;
  const int b = r0 >> 11;
  const int t0 = r0 & 2047, t1 = t0 + 1;
  const int tid = threadIdx.x;
  if (t1 < 64) {
    for (int lr = 0; lr < 2; ++lr) {
      int t = t0 + lr;
      int* outp = selidx + (size_t)(r0 + lr) * 68;
      for (int jj = tid; jj <= t; jj += 256) outp[jj] = jj;
      if (tid == 0) selcnt[r0 + lr] = t + 1;
    }
    return;
  }
  __shared__ double qrowP[64][2];
  __shared__ u64 su[2][2048];
  __shared__ unsigned hist[256], sA[256], sB[256];
  __shared__ unsigned s_bsel, s_larger, s_cnt;
  __shared__ u64 s_thr;
  __shared__ int s_remfin;
  __shared__ int cand[128];
  __shared__ u64 ckey[128];

  if (tid < 128) qrowP[tid >> 1][tid & 1] = qs[(size_t)(r0 + (tid & 1)) * 64 + (tid >> 1)];
  __syncthreads();
  {
    const double* kb = ksT + (size_t)b * 64 * 2048;
    const int emax = t1 >> 8;
    for (int e = 0; e <= emax; ++e) {
      const int jj = e * 256 + tid;
      double acc0 = 0.0, acc1 = 0.0;
      const double* kp = kb + jj;
      #pragma unroll 16
      for (int d = 0; d < 64; ++d) {
        double kv = kp[(size_t)d * 2048];
        f64x2 qp = *(const f64x2*)&qrowP[d][0];
        acc0 = fma(qp.x, kv, acc0);
        acc1 = fma(qp.y, kv, acc1);
      }
      const int sx = suX(jj);
      u64 u0 = (u64)__double_as_longlong(acc0);
      su[0][sx] = (u0 >> 63) ? ~u0 : (u0 | 0x8000000000000000ull);
      u64 u1 = (u64)__double_as_longlong(acc1);
      su[1][sx] = (u1 >> 63) ? ~u1 : (u1 | 0x8000000000000000ull);
    }
  }
  __syncthreads();

  const int c0 = tid * 8;
  for (int lr = 0; lr < 2; ++lr) {
    const int t = t0 + lr;
    int* outp = selidx + (size_t)(r0 + lr) * 68;
    const u64* S = su[lr];
    u64 prefix = 0;
    int remaining = 64;
    int broke = 0, sh_final = 0;
    for (int byte = 7; byte >= 0; --byte) {
      const int sh = byte * 8;
      hist[tid] = 0;
      __syncthreads();
      {
        unsigned bn[8]; bool vl[8];
        #pragma unroll
        for (int e = 0; e < 8; ++e) {
          int jj = c0 + e;
          u64 u = (jj <= t) ? S[suX(jj)] : 0;
          bool ok = (jj <= t) && ((byte == 7) || (((u ^ prefix) >> (sh + 8)) == 0));
          bn[e] = (unsigned)((u >> sh) & 255);
          vl[e] = ok;
        }
        #pragma unroll
        for (int e = 0; e < 8; ++e) {
          if (vl[e]) {
            bool first = true;
            #pragma unroll
            for (int p = 0; p < 8; ++p)
              if (p < e && vl[p] && bn[p] == bn[e]) first = false;
            if (first) {
              unsigned c = 0;
              #pragma unroll
              for (int q = 0; q < 8; ++q)
                if (q >= e && vl[q] && bn[q] == bn[e]) ++c;
              atomicAdd(&hist[bn[e]], c);
            }
          }
        }
      }
      __syncthreads();
      unsigned* sp = sA; unsigned* dp = sB;
      sp[tid] = hist[tid];
      __syncthreads();
      #pragma unroll
      for (int off = 1; off < 256; off <<= 1) {
        dp[tid] = sp[tid] + ((tid + off < 256) ? sp[tid + off] : 0u);
        __syncthreads();
        unsigned* tpp = sp; sp = dp; dp = tpp;
      }
      unsigned inc = sp[tid];
      unsigned cumAbove = (tid == 255) ? 0u : sp[tid + 1];
      if ((int)cumAbove < remaining && (int)inc >= remaining) {
        s_bsel = (unsigned)tid;
        s_larger = cumAbove;
        s_cnt = inc - cumAbove;
      }
      __syncthreads();
      prefix |= ((u64)s_bsel << sh);
      remaining -= (int)s_larger;
      int cnt = (int)s_cnt;
      __syncthreads();
      if (cnt <= 128) { broke = 1; sh_final = sh; break; }
    }
    u64 thr;
    int remfin;
    if (broke) {
      unsigned cg = 0;
      #pragma unroll
      for (int e = 0; e < 8; ++e) {
        int jj = c0 + e;
        if (jj <= t && (((S[suX(jj)] ^ prefix) >> sh_final) == 0)) ++cg;
      }
      unsigned* sp = sA; unsigned* dp = sB;
      sp[tid] = cg;
      __syncthreads();
      #pragma unroll
      for (int off = 1; off < 256; off <<= 1) {
        dp[tid] = sp[tid] + ((tid >= off) ? sp[tid - off] : 0u);
        __syncthreads();
        unsigned* tpp = sp; sp = dp; dp = tpp;
      }
      const int C = (int)sp[255];
      int pos = (int)(sp[tid] - cg);
      #pragma unroll
      for (int e = 0; e < 8; ++e) {
        int jj = c0 + e;
        if (jj <= t && (((S[suX(jj)] ^ prefix) >> sh_final) == 0)) cand[pos++] = jj;
      }
      __syncthreads();
      if (tid < C) ckey[tid] = S[suX(cand[tid])];
      __syncthreads();
      if (tid < C) {
        u64 k = ckey[tid];
        int g = 0, eq = 0;
        for (int j = 0; j < C; ++j) {
          g += (ckey[j] > k) ? 1 : 0;
          eq += (ckey[j] == k) ? 1 : 0;
        }
        if (g < remaining && remaining <= g + eq) {
          s_thr = k;
          s_remfin = remaining - g;
        }
      }
      __syncthreads();
      thr = s_thr;
      remfin = s_remfin;
    } else {
      thr = prefix;
      remfin = remaining;
    }
    __syncthreads();
    unsigned cg = 0, ct_ = 0;
    #pragma unroll
    for (int e = 0; e < 8; ++e) {
      int jj = c0 + e;
      if (jj <= t) {
        u64 u = S[suX(jj)];
        cg += (u > thr) ? 1u : 0u;
        ct_ += (u == thr) ? 1u : 0u;
      }
    }
    const unsigned pack = cg | (ct_ << 16);
    {
      unsigned* sp = sA; unsigned* dp = sB;
      sp[tid] = pack;
      __syncthreads();
      #pragma unroll
      for (int off = 1; off < 256; off <<= 1) {
        dp[tid] = sp[tid] + ((tid >= off) ? sp[tid - off] : 0u);
        __syncthreads();
        unsigned* tpp = sp; sp = dp; dp = tpp;
      }
      const unsigned excl = sp[tid] - pack;
      const unsigned tot = sp[255];
      const unsigned Gtot = tot & 0xFFFFu;
      const u64 ut = S[suX(t)];
      const unsigned gt = (ut > thr) ? 1u : 0u;
      const unsigned tt = (ut == thr) ? 1u : 0u;
      const int GtotX = (int)(Gtot - gt);
      int gpos = (int)(excl & 0xFFFFu);
      int tpos = (int)(excl >> 16);
      #pragma unroll
      for (int e = 0; e < 8; ++e) {
        int jj = c0 + e;
        if (jj > t) break;
        u64 u = S[suX(jj)];
        if (u > thr) {
          if (jj != t) outp[1 + gpos] = jj;
          ++gpos;
        } else if (u == thr) {
          if (jj != t && tpos < remfin) outp[1 + GtotX + tpos] = jj;
          ++tpos;
        }
      }
      if (tid == 0) {
        outp[0] = t;
        const unsigned Ttot = tot >> 16;
        int tb = (int)(Ttot - tt);
        int emitT = tb < remfin ? tb : remfin;
        selcnt[r0 + lr] = 1 + GtotX + emitT;  // 64 or 65
      }
    }
    __syncthreads();
  }
}

// ------------------------------------------------------------- sparse attention
// R8 structure. Changes vs R10: (a) staging = static 5-iter reg-staged unroll
// (all 10 global loads issue before any LDS write -> T14 latency overlap);
// (b) PV via fdot2 on f16-packed P (replaces ~130 cvt + 130 fma with ~66 fdot2;
// P f16 rounding adds ~1e-3 abs on y, well under budget).
__global__ __launch_bounds__(256) void k_attn(const f16* __restrict__ qr,
                                              const f16* __restrict__ kr,
                                              const f16* __restrict__ vv,
                                              const int* __restrict__ selcnt,
                                              const int* __restrict__ selidx,
                                              f16* __restrict__ y)
{
  const int blk = blockIdx.x;  // row*4 + kvh
  const int row = blk >> 2, kvh = blk & 3;
  const int b = row >> 11;
  const int tid = threadIdx.x, lane = tid & 63, wave = tid >> 6;
  const int cnt = selcnt[row];
  __shared__ int sidx[68];
  __shared__ __align__(16) f16 Kl[65 * 128];   // chunk-XOR swizzled
  __shared__ __align__(16) f16 Vl[68 * 128];   // linear, rows [cnt,68) zeroed
  __shared__ f16 qlds[4][128];
  __shared__ __align__(4) f16 ph[4][72];       // P in f16, [cnt..72) zeroed
  if (tid < cnt) sidx[tid] = selidx[(size_t)row * 68 + tid];
  *(f16x2*)&qlds[wave][lane * 2] =
      *(const f16x2*)&qr[((size_t)row * 16 + kvh * 4 + wave) * 128 + lane * 2];
  __syncthreads();  // sidx ready

  // reg-staged gather: issue all loads first, then LDS writes
  f16x8 kreg[5], vreg[5];
  int rr[5], cc[5]; bool vld[5];
  #pragma unroll
  for (int it = 0; it < 5; ++it) {
    const int c = it * 256 + tid;
    const int r = c >> 4, ch = c & 15;
    const bool ok = (r < cnt);
    const int rsafe = ok ? sidx[r] : sidx[0];
    const size_t kbase = ((size_t)(b * 2048 + rsafe)) * 512 + kvh * 128 + ch * 8;
    kreg[it] = *(const f16x8*)&kr[kbase];
    vreg[it] = *(const f16x8*)&vv[kbase];
    rr[it] = r; cc[it] = ch; vld[it] = ok;
  }
  #pragma unroll
  for (int it = 0; it < 5; ++it) {
    if (vld[it]) {
      *(f16x8*)&Kl[rr[it] * 128 + ((cc[it] ^ (rr[it] & 15)) * 8)] = kreg[it];
      *(f16x8*)&Vl[rr[it] * 128 + cc[it] * 8] = vreg[it];
    }
  }
  // zero Vl rows [cnt, 68)
  for (int i = tid; i < (68 - cnt) * 64; i += 256)
    ((u32*)Vl)[cnt * 64 + i] = 0u;
  __syncthreads();

  const float SCALE = 0.08838834764831845f;  // 1/sqrt(128)
  auto dotk = [&](int r) -> float {
    const int sw = r & 15;
    float s = 0.0f;
    #pragma unroll
    for (int i = 0; i < 16; ++i) {
      f16x8 k8 = *(const f16x8*)&Kl[r * 128 + ((i ^ sw) * 8)];
      f16x8 q8 = *(const f16x8*)&qlds[wave][i * 8];
      #pragma unroll
      for (int e = 0; e < 4; ++e) {
        f16x2 ka; ka.x = k8[2 * e]; ka.y = k8[2 * e + 1];
        f16x2 qa; qa.x = q8[2 * e]; qa.y = q8[2 * e + 1];
        s = __builtin_amdgcn_fdot2(ka, qa, s, false);
      }
    }
    return s * SCALE;
  };

  float s1 = -__builtin_inff(), s2 = -__builtin_inff();
  if (lane < cnt) s1 = dotk(lane);
  if (lane + 64 < cnt) s2 = dotk(lane + 64);  // only lane 0, cnt==65
  float mx = fmaxf(s1, s2);
  #pragma unroll
  for (int off = 32; off; off >>= 1) mx = fmaxf(mx, __shfl_xor(mx, off));
  float p1 = (lane < cnt) ? __expf(s1 - mx) : 0.0f;
  float p2 = (lane + 64 < cnt) ? __expf(s2 - mx) : 0.0f;
  float l = p1 + p2;
  #pragma unroll
  for (int off = 32; off; off >>= 1) l += __shfl_xor(l, off);
  float linv = 1.0f / l;
  ph[wave][lane] = (f16)p1;
  if (lane == 0) ph[wave][64] = (f16)p2;
  if (lane >= 1 && lane < 8) ph[wave][64 + lane] = (f16)0.f;
  __syncthreads();

  float y0 = 0.0f, y1 = 0.0f;
  const int d2 = lane * 2;
  for (int j = 0; j < cnt; j += 2) {
    f16x2 pp = *(const f16x2*)&ph[wave][j];
    f16x2 va = *(const f16x2*)&Vl[(j + 0) * 128 + d2];
    f16x2 vb = *(const f16x2*)&Vl[(j + 1) * 128 + d2];
    f16x2 v0; v0.x = va.x; v0.y = vb.x;   // (V[j][d2],   V[j+1][d2])
    f16x2 v1; v1.x = va.y; v1.y = vb.y;   // (V[j][d2+1], V[j+1][d2+1])
    y0 = __builtin_amdgcn_fdot2(pp, v0, y0, false);
    y1 = __builtin_amdgcn_fdot2(pp, v1, y1, false);
  }
  y0 *= linv; y1 *= linv;
  f16x2 o; o.x = (f16)y0; o.y = (f16)y1;
  *(f16x2*)&y[(size_t)row * 2048 + (kvh * 4 + wave) * 128 + d2] = o;
}

// ================================================================ launch
extern "C" void kernel_launch(void* const* d_in, const int* in_sizes, int n_in,
                              void* d_out, int out_size, void* d_ws, size_t ws_size,
                              hipStream_t stream)
{
  (void)in_sizes; (void)n_in; (void)out_size; (void)ws_size;
  const float* x   = (const float*)d_in[0];
  const float* Wq  = (const float*)d_in[1];
  const float* bq  = (const float*)d_in[2];
  const float* Wkd = (const float*)d_in[3];
  const float* bkd = (const float*)d_in[4];
  const float* Wku = (const float*)d_in[5];
  const float* bku = (const float*)d_in[6];
  const float* Wo  = (const float*)d_in[7];
  const float* bo  = (const float*)d_in[8];
  float* out = (float*)d_out;

  char* ws = (char*)d_ws;
  size_t o = 0;
  auto alloc = [&](size_t bytes) -> void* {
    o = (o + 255) & ~(size_t)255;
    void* p = ws + o;
    o += bytes;
    return p;
  };
  f16* WqT   = (f16*)alloc(2048ull * 2048 * 2);
  f16* WoT   = (f16*)alloc(2048ull * 2048 * 2);
  f16* WkdT  = (f16*)alloc(512ull * 2048 * 2);
  f16* WkuT  = (f16*)alloc(1024ull * 512 * 2);
  f16* xh    = (f16*)alloc(4096ull * 2048 * 2);
  f16* yh    = (f16*)alloc(4096ull * 2048 * 2);  // attention output
  f16* cbf   = (f16*)alloc(4096ull * 512 * 2);
  float* rc  = (float*)alloc(2048ull * 64 * 4);
  float* rs  = (float*)alloc(2048ull * 64 * 4);
  f16* qrope = (f16*)alloc(4096ull * 2048 * 2);
  f16* krope = (f16*)alloc(4096ull * 512 * 2);
  f16* vbf   = (f16*)alloc(4096ull * 512 * 2);
  int* selcnt = (int*)alloc(4096ull * 4);
  int* selidx = (int*)alloc(4096ull * 68 * 4);
  double* Bsel = (double*)alloc(2048ull * 128 * 8);
  double* bsel = (double*)alloc(128 * 8);
  double* qs64 = (double*)alloc(4096ull * 64 * 8);
  double* ks64 = (double*)alloc(4096ull * 64 * 8);
  double* ksT  = (double*)alloc(2ull * 64 * 2048 * 8);
  double* partial = (double*)qrope;  // alias: 16 MiB, dead until Wq GEMM writes qrope

  // --- weight prep + rope tables ---
  k_transpose_cast<<<dim3(64, 64), 256, 0, stream>>>(Wq, WqT, 2048, 2048);
  k_transpose_cast<<<dim3(16, 64), 256, 0, stream>>>(Wkd, WkdT, 2048, 512);
  k_transpose_cast<<<dim3(32, 16), 256, 0, stream>>>(Wku, WkuT, 512, 1024);
  k_transpose_cast<<<dim3(64, 64), 256, 0, stream>>>(Wo, WoT, 2048, 2048);
  k_cast_f16<<<8192, 256, 0, stream>>>(x, xh, 2097152);
  k_rope_table<<<2048, 64, 0, stream>>>(rc, rs);

  // --- fp64 selector path (split-K) ---
  k_prep_sel<<<2048, 64, 0, stream>>>(Wq, Wkd, Wku, Bsel);
  k_bias_sel<<<1, 128, 0, stream>>>(bq, bkd, Wku, bku, bsel);
  k_gemm_sel_f64<<<dim3(128, 2, 4), 256, 0, stream>>>(x, Bsel, partial);
  k_sel_reduce<<<2048, 256, 0, stream>>>(partial, bsel, qs64, ks64);
  k_transpose64<<<dim3(2, 64, 2), 256, 0, stream>>>(ks64, ksT);

  // --- fp16 MFMA main path (RoPE fused into epilogues; partial alias now dead) ---
  k_gemm_bt<2><<<dim3(32, 16), 256, 0, stream>>>(xh, WqT, bq, nullptr, qrope,
                                                 nullptr, nullptr, rc, rs,
                                                 4096, 2048, 2048, 2048, 2048, 2048);
  k_gemm_bt<1><<<dim3(32, 4), 256, 0, stream>>>(xh, WkdT, bkd, nullptr, cbf,
                                                nullptr, nullptr, nullptr, nullptr,
                                                4096, 512, 2048, 2048, 2048, 512);
  k_gemm_bt<3><<<dim3(32, 8), 256, 0, stream>>>(cbf, WkuT, bku, nullptr, nullptr,
                                                krope, vbf, rc, rs,
                                                4096, 1024, 512, 512, 512, 1024);

  // --- selector top-k ---
  k_topk64<<<2048, 256, 0, stream>>>(qs64, ksT, selcnt, selidx);

  // --- sparse attention ---
  k_attn<<<16384, 256, 0, stream>>>(qrope, krope, vbf, selcnt, selidx, yh);

  // --- output projection ---
  k_gemm_bt<0><<<dim3(32, 16), 256, 0, stream>>>(yh, WoT, bo, out, nullptr,
                                                 nullptr, nullptr, nullptr, nullptr,
                                                 4096, 2048, 2048, 2048, 2048, 2048);
}